// Round 1
// baseline (2979.734 us; speedup 1.0000x reference)
//
#include <hip/hip_runtime.h>
#include <hip/hip_bf16.h>

#define DIN   128
#define DH    128
#define DOUTC 64
#define BN_EPS 1e-5f

// ---------------------------------------------------------------------------
// Scatter-mean aggregation: for each edge e, agg[dst[e]] += feat[src[e]] (128 f)
// 32 lanes per edge, float4 gather (512B contiguous row), 4 atomics per lane.
// Lane 0 optionally bumps the degree counter.
// ---------------------------------------------------------------------------
__global__ __launch_bounds__(256) void scatter_kernel(
    const int* __restrict__ ei,      // [2, E] : row0 = src, row1 = dst
    const float* __restrict__ feat,  // [N, 128]
    float* __restrict__ agg,         // [N, 128] (pre-zeroed)
    float* __restrict__ cnt,         // [N]      (pre-zeroed)
    int E, int do_cnt)
{
    int e    = blockIdx.x * 8 + (threadIdx.x >> 5);
    int lane = threadIdx.x & 31;
    if (e >= E) return;
    int s = ei[e];
    int d = ei[E + e];
    const float4 v = ((const float4*)(feat + (size_t)s * DIN))[lane];
    float* dp = agg + (size_t)d * DIN + lane * 4;
    atomicAdd(dp + 0, v.x);
    atomicAdd(dp + 1, v.y);
    atomicAdd(dp + 2, v.z);
    atomicAdd(dp + 3, v.w);
    if (do_cnt && lane == 0) atomicAdd(cnt + d, 1.0f);
}

// ---------------------------------------------------------------------------
// GEMM1: h_pre = (agg/max(cnt,1)) @ Wl1 + x @ Wr1 + b1   [N,128]
// Treated as [N,256] @ [256,128] with LDS-staged input rows.
// 16 rows / block, 256 threads: tx=col(128), ty=rowgroup(2), 8 outputs/thread.
// Epilogue: per-column sum & sumsq partials -> atomics (for BatchNorm).
// ---------------------------------------------------------------------------
__global__ __launch_bounds__(256) void gemm1_kernel(
    const float* __restrict__ x, const float* __restrict__ agg,
    const float* __restrict__ cnt,
    const float* __restrict__ Wl, const float* __restrict__ Wr,
    const float* __restrict__ bias,
    float* __restrict__ h,
    float* __restrict__ bn_sum, float* __restrict__ bn_sumsq,
    int n_nodes)
{
    __shared__ float in_lds[16][256];
    __shared__ float red_sum[2][128];
    __shared__ float red_sq[2][128];

    const int block_row = blockIdx.x * 16;
    const int tid = threadIdx.x;

    // stage [agg/cnt || x] rows into LDS (coalesced: consecutive tid -> consecutive c)
    #pragma unroll
    for (int i = 0; i < 16; ++i) {
        int idx = tid + i * 256;           // 0..4095
        int r   = idx >> 8;
        int c   = idx & 255;
        int g   = block_row + r;
        float v;
        if (g < n_nodes) {
            if (c < DIN) {
                v = agg[(size_t)g * DIN + c] / fmaxf(cnt[g], 1.0f);
            } else {
                v = x[(size_t)g * DIN + (c - DIN)];
            }
        } else v = 0.0f;
        in_lds[r][c] = v;
    }
    __syncthreads();

    const int tx = tid & 127;   // output column
    const int ty = tid >> 7;    // 0..1
    float acc[8];
    #pragma unroll
    for (int i = 0; i < 8; ++i) acc[i] = 0.0f;

    for (int k = 0; k < DIN; ++k) {
        float w = Wl[k * DH + tx];
        #pragma unroll
        for (int i = 0; i < 8; ++i) acc[i] += in_lds[i * 2 + ty][k] * w;
    }
    for (int k = 0; k < DIN; ++k) {
        float w = Wr[k * DH + tx];
        #pragma unroll
        for (int i = 0; i < 8; ++i) acc[i] += in_lds[i * 2 + ty][DIN + k] * w;
    }

    float bv = bias[tx];
    float psum = 0.0f, psq = 0.0f;
    #pragma unroll
    for (int i = 0; i < 8; ++i) {
        int g = block_row + i * 2 + ty;
        float v = acc[i] + bv;
        if (g < n_nodes) {
            h[(size_t)g * DH + tx] = v;
            psum += v;
            psq  += v * v;
        }
    }
    red_sum[ty][tx] = psum;
    red_sq[ty][tx]  = psq;
    __syncthreads();
    if (ty == 0) {
        atomicAdd(&bn_sum[tx],   red_sum[0][tx] + red_sum[1][tx]);
        atomicAdd(&bn_sumsq[tx], red_sq[0][tx]  + red_sq[1][tx]);
    }
}

// ---------------------------------------------------------------------------
// BatchNorm (training-mode batch stats, biased var) + ReLU, in place on h.
// ---------------------------------------------------------------------------
__global__ __launch_bounds__(256) void bn_relu_kernel(
    float* __restrict__ h,
    const float* __restrict__ gamma, const float* __restrict__ beta,
    const float* __restrict__ bn_sum, const float* __restrict__ bn_sumsq,
    int n_nodes)
{
    int idx = blockIdx.x * 256 + threadIdx.x;
    int total = n_nodes * DH;
    if (idx >= total) return;
    int col = idx & (DH - 1);
    float invN = 1.0f / (float)n_nodes;
    float mu  = bn_sum[col] * invN;
    float var = bn_sumsq[col] * invN - mu * mu;
    float rs  = rsqrtf(var + BN_EPS);
    float v = (h[idx] - mu) * rs * gamma[col] + beta[col];
    h[idx] = fmaxf(v, 0.0f);
}

// ---------------------------------------------------------------------------
// GEMM2: out = (agg2/max(cnt,1)) @ Wl2 + h @ Wr2 + b2   [N,64]
// Same structure; tx=col(64), ty=rowgroup(4), 4 outputs/thread.
// ---------------------------------------------------------------------------
__global__ __launch_bounds__(256) void gemm2_kernel(
    const float* __restrict__ hfeat, const float* __restrict__ agg,
    const float* __restrict__ cnt,
    const float* __restrict__ Wl, const float* __restrict__ Wr,
    const float* __restrict__ bias,
    float* __restrict__ out,
    int n_nodes)
{
    __shared__ float in_lds[16][256];
    const int block_row = blockIdx.x * 16;
    const int tid = threadIdx.x;

    #pragma unroll
    for (int i = 0; i < 16; ++i) {
        int idx = tid + i * 256;
        int r   = idx >> 8;
        int c   = idx & 255;
        int g   = block_row + r;
        float v;
        if (g < n_nodes) {
            if (c < DH) {
                v = agg[(size_t)g * DH + c] / fmaxf(cnt[g], 1.0f);
            } else {
                v = hfeat[(size_t)g * DH + (c - DH)];
            }
        } else v = 0.0f;
        in_lds[r][c] = v;
    }
    __syncthreads();

    const int tx = tid & 63;   // output column
    const int ty = tid >> 6;   // 0..3
    float acc[4] = {0.f, 0.f, 0.f, 0.f};

    for (int k = 0; k < DH; ++k) {
        float w = Wl[k * DOUTC + tx];
        #pragma unroll
        for (int i = 0; i < 4; ++i) acc[i] += in_lds[i * 4 + ty][k] * w;
    }
    for (int k = 0; k < DH; ++k) {
        float w = Wr[k * DOUTC + tx];
        #pragma unroll
        for (int i = 0; i < 4; ++i) acc[i] += in_lds[i * 4 + ty][DH + k] * w;
    }

    float bv = bias[tx];
    #pragma unroll
    for (int i = 0; i < 4; ++i) {
        int g = block_row + i * 4 + ty;
        if (g < n_nodes) out[(size_t)g * DOUTC + tx] = acc[i] + bv;
    }
}

// ---------------------------------------------------------------------------
extern "C" void kernel_launch(void* const* d_in, const int* in_sizes, int n_in,
                              void* d_out, int out_size, void* d_ws, size_t ws_size,
                              hipStream_t stream)
{
    const float* x     = (const float*)d_in[0];
    const int*   ei    = (const int*)  d_in[1];
    const float* Wl1   = (const float*)d_in[2];
    const float* Wr1   = (const float*)d_in[3];
    const float* b1    = (const float*)d_in[4];
    const float* gamma = (const float*)d_in[5];
    const float* beta  = (const float*)d_in[6];
    const float* Wl2   = (const float*)d_in[7];
    const float* Wr2   = (const float*)d_in[8];
    const float* b2    = (const float*)d_in[9];
    float*       out   = (float*)d_out;

    const int N = in_sizes[0] / DIN;      // 50000
    const int E = in_sizes[1] / 2;        // 800000

    // workspace layout (floats)
    float* ws      = (float*)d_ws;
    float* agg     = ws;                               // N*128
    float* cnt     = agg + (size_t)N * DIN;            // N
    float* bn_sum  = cnt + N;                          // 128
    float* bn_sumsq= bn_sum + DH;                      // 128
    float* h       = bn_sumsq + DH;                    // N*128

    const size_t zero_prefix_bytes = ((size_t)N * DIN + N + 2 * DH) * sizeof(float);

    // zero agg + cnt + bn sums
    hipMemsetAsync(agg, 0, zero_prefix_bytes, stream);

    dim3 blk(256);
    int scatter_blocks = (E + 7) / 8;
    int row_blocks     = (N + 15) / 16;

    // layer 1 aggregation (+ degree counts)
    scatter_kernel<<<scatter_blocks, blk, 0, stream>>>(ei, x, agg, cnt, E, 1);

    // h_pre = mean_agg @ Wl1 + x @ Wr1 + b1  (+ BN partial sums)
    gemm1_kernel<<<row_blocks, blk, 0, stream>>>(x, agg, cnt, Wl1, Wr1, b1,
                                                 h, bn_sum, bn_sumsq, N);

    // BN + ReLU in place
    int bn_blocks = (N * DH + 255) / 256;
    bn_relu_kernel<<<bn_blocks, blk, 0, stream>>>(h, gamma, beta, bn_sum, bn_sumsq, N);

    // re-zero agg for layer 2
    hipMemsetAsync(agg, 0, (size_t)N * DIN * sizeof(float), stream);

    // layer 2 aggregation (counts reused)
    scatter_kernel<<<scatter_blocks, blk, 0, stream>>>(ei, h, agg, cnt, E, 0);

    // out = mean_agg2 @ Wl2 + h @ Wr2 + b2
    gemm2_kernel<<<row_blocks, blk, 0, stream>>>(h, agg, cnt, Wl2, Wr2, b2, out, N);
}

// Round 2
// 455.913 us; speedup vs baseline: 6.5358x; 6.5358x over previous
//
#include <hip/hip_runtime.h>
#include <hip/hip_bf16.h>

#define DIN   128
#define DH    128
#define DOUTC 64
#define BN_EPS 1e-5f

// ---------------------------------------------------------------------------
// CSR build, step 1: degree histogram over dst (int atomics, low cost).
// ---------------------------------------------------------------------------
__global__ __launch_bounds__(256) void hist_kernel(
    const int* __restrict__ ei, int* __restrict__ deg, int E)
{
    int e = blockIdx.x * 256 + threadIdx.x;
    if (e < E) atomicAdd(&deg[ei[E + e]], 1);
}

// ---------------------------------------------------------------------------
// CSR build, step 2: allocate each node's slice via wave-scan + 1 atomic/wave.
// Layout order across nodes is non-deterministic but irrelevant (sum order
// only perturbs fp32 rounding).
// ---------------------------------------------------------------------------
__global__ __launch_bounds__(256) void alloc_kernel(
    const int* __restrict__ deg, int* __restrict__ row_start,
    int* __restrict__ cursor, int n)
{
    int i    = blockIdx.x * 256 + threadIdx.x;
    int lane = threadIdx.x & 63;
    int v = (i < n) ? deg[i] : 0;
    int inc = v;
    #pragma unroll
    for (int off = 1; off < 64; off <<= 1) {
        int t = __shfl_up(inc, off, 64);
        if (lane >= off) inc += t;
    }
    int total = __shfl(inc, 63, 64);
    int base = 0;
    if (lane == 63) base = atomicAdd(cursor, total);
    base = __shfl(base, 63, 64);
    if (i < n) row_start[i] = base + inc - v;
}

// ---------------------------------------------------------------------------
// CSR build, step 3: bucket src ids into per-dst slices.
// ---------------------------------------------------------------------------
__global__ __launch_bounds__(256) void bucket_kernel(
    const int* __restrict__ ei, const int* __restrict__ row_start,
    int* __restrict__ fill, int* __restrict__ sorted_src, int E)
{
    int e = blockIdx.x * 256 + threadIdx.x;
    if (e >= E) return;
    int s = ei[e];
    int d = ei[E + e];
    int pos = row_start[d] + atomicAdd(&fill[d], 1);
    sorted_src[pos] = s;
}

// ---------------------------------------------------------------------------
// Gather-mean aggregation, 128-wide rows. One wave per node; lane = float2
// slice of the row. Neighbor ids batch-loaded (64/lane-vector) and broadcast
// via shfl so the address chain is shallow.
// ---------------------------------------------------------------------------
__global__ __launch_bounds__(256) void agg_gather128(
    const int* __restrict__ row_start, const int* __restrict__ deg,
    const int* __restrict__ sorted_src, const float* __restrict__ feat,
    float* __restrict__ agg, int n)
{
    int wave = (blockIdx.x * 256 + threadIdx.x) >> 6;
    int lane = threadIdx.x & 63;
    if (wave >= n) return;
    int base = row_start[wave];
    int d    = deg[wave];
    float2 acc = {0.f, 0.f};
    for (int k0 = 0; k0 < d; k0 += 64) {
        int idx = k0 + lane;
        int mys = (idx < d) ? sorted_src[base + idx] : 0;
        int kmax = min(64, d - k0);
        for (int k = 0; k < kmax; ++k) {
            int s = __shfl(mys, k, 64);
            float2 v = ((const float2*)(feat + (size_t)s * DIN))[lane];
            acc.x += v.x;
            acc.y += v.y;
        }
    }
    float inv = 1.0f / fmaxf((float)d, 1.0f);
    float2 o = {acc.x * inv, acc.y * inv};
    ((float2*)(agg + (size_t)wave * DIN))[lane] = o;
}

// ---------------------------------------------------------------------------
// Gather-mean aggregation, 64-wide (layer-2 projected features), accumulating
// into out (which already holds h @ Wr2 + b2).
// ---------------------------------------------------------------------------
__global__ __launch_bounds__(256) void agg_gather64_add(
    const int* __restrict__ row_start, const int* __restrict__ deg,
    const int* __restrict__ sorted_src, const float* __restrict__ P,
    float* __restrict__ out, int n)
{
    int wave = (blockIdx.x * 256 + threadIdx.x) >> 6;
    int lane = threadIdx.x & 63;
    if (wave >= n) return;
    int base = row_start[wave];
    int d    = deg[wave];
    float acc = 0.f;
    for (int k0 = 0; k0 < d; k0 += 64) {
        int idx = k0 + lane;
        int mys = (idx < d) ? sorted_src[base + idx] : 0;
        int kmax = min(64, d - k0);
        for (int k = 0; k < kmax; ++k) {
            int s = __shfl(mys, k, 64);
            acc += P[(size_t)s * DOUTC + lane];
        }
    }
    float inv = 1.0f / fmaxf((float)d, 1.0f);
    out[(size_t)wave * DOUTC + lane] += acc * inv;
}

// ---------------------------------------------------------------------------
// GEMM1: h_pre = agg @ Wl1 + x @ Wr1 + b1   [N,128]  (agg pre-meaned)
// 16 rows/block staged to LDS; 256 thr: tx=col(128), ty=rowgroup(2), 8 out/thr.
// Epilogue: per-column sum & sumsq partials -> atomics (for BatchNorm).
// ---------------------------------------------------------------------------
__global__ __launch_bounds__(256) void gemm1_kernel(
    const float* __restrict__ x, const float* __restrict__ agg,
    const float* __restrict__ Wl, const float* __restrict__ Wr,
    const float* __restrict__ bias,
    float* __restrict__ h,
    float* __restrict__ bn_sum, float* __restrict__ bn_sumsq,
    int n_nodes)
{
    __shared__ float in_lds[16][256];
    __shared__ float red_sum[2][128];
    __shared__ float red_sq[2][128];

    const int block_row = blockIdx.x * 16;
    const int tid = threadIdx.x;

    #pragma unroll
    for (int i = 0; i < 16; ++i) {
        int idx = tid + i * 256;
        int r   = idx >> 8;
        int c   = idx & 255;
        int g   = block_row + r;
        float v;
        if (g < n_nodes) {
            v = (c < DIN) ? agg[(size_t)g * DIN + c]
                          : x[(size_t)g * DIN + (c - DIN)];
        } else v = 0.0f;
        in_lds[r][c] = v;
    }
    __syncthreads();

    const int tx = tid & 127;
    const int ty = tid >> 7;
    float acc[8];
    #pragma unroll
    for (int i = 0; i < 8; ++i) acc[i] = 0.0f;

    for (int k = 0; k < DIN; ++k) {
        float w = Wl[k * DH + tx];
        #pragma unroll
        for (int i = 0; i < 8; ++i) acc[i] += in_lds[i * 2 + ty][k] * w;
    }
    for (int k = 0; k < DIN; ++k) {
        float w = Wr[k * DH + tx];
        #pragma unroll
        for (int i = 0; i < 8; ++i) acc[i] += in_lds[i * 2 + ty][DIN + k] * w;
    }

    float bv = bias[tx];
    float psum = 0.0f, psq = 0.0f;
    #pragma unroll
    for (int i = 0; i < 8; ++i) {
        int g = block_row + i * 2 + ty;
        float v = acc[i] + bv;
        if (g < n_nodes) {
            h[(size_t)g * DH + tx] = v;
            psum += v;
            psq  += v * v;
        }
    }
    red_sum[ty][tx] = psum;
    red_sq[ty][tx]  = psq;
    __syncthreads();
    if (ty == 0) {
        atomicAdd(&bn_sum[tx],   red_sum[0][tx] + red_sum[1][tx]);
        atomicAdd(&bn_sumsq[tx], red_sq[0][tx]  + red_sq[1][tx]);
    }
}

// ---------------------------------------------------------------------------
// BatchNorm (batch stats, biased var) + ReLU, in place on h.
// ---------------------------------------------------------------------------
__global__ __launch_bounds__(256) void bn_relu_kernel(
    float* __restrict__ h,
    const float* __restrict__ gamma, const float* __restrict__ beta,
    const float* __restrict__ bn_sum, const float* __restrict__ bn_sumsq,
    int n_nodes)
{
    int idx = blockIdx.x * 256 + threadIdx.x;
    int total = n_nodes * DH;
    if (idx >= total) return;
    int col = idx & (DH - 1);
    float invN = 1.0f / (float)n_nodes;
    float mu  = bn_sum[col] * invN;
    float var = bn_sumsq[col] * invN - mu * mu;
    float rs  = rsqrtf(var + BN_EPS);
    float v = (h[idx] - mu) * rs * gamma[col] + beta[col];
    h[idx] = fmaxf(v, 0.0f);
}

// ---------------------------------------------------------------------------
// GEMM2 projection: P = h @ Wl2 (cols 0..63) and out = h @ Wr2 + b2
// (cols 64..127), fused as one [N,128]@[128,128] with per-wave weight select.
// ---------------------------------------------------------------------------
__global__ __launch_bounds__(256) void gemm2p_kernel(
    const float* __restrict__ h,
    const float* __restrict__ Wl, const float* __restrict__ Wr,
    const float* __restrict__ bias,
    float* __restrict__ P, float* __restrict__ out, int n_nodes)
{
    __shared__ float in_lds[16][128];
    const int block_row = blockIdx.x * 16;
    const int tid = threadIdx.x;

    #pragma unroll
    for (int i = 0; i < 8; ++i) {
        int idx = tid + i * 256;      // 0..2047
        int r   = idx >> 7;
        int c   = idx & 127;
        int g   = block_row + r;
        in_lds[r][c] = (g < n_nodes) ? h[(size_t)g * DH + c] : 0.0f;
    }
    __syncthreads();

    const int tx = tid & 127;
    const int ty = tid >> 7;          // 0..1
    const float* W = (tx < 64) ? Wl : Wr;   // wave-uniform select
    const int c = tx & 63;

    float acc[8];
    #pragma unroll
    for (int i = 0; i < 8; ++i) acc[i] = 0.0f;

    for (int k = 0; k < DH; ++k) {
        float w = W[k * DOUTC + c];
        #pragma unroll
        for (int i = 0; i < 8; ++i) acc[i] += in_lds[i * 2 + ty][k] * w;
    }

    if (tx < 64) {
        #pragma unroll
        for (int i = 0; i < 8; ++i) {
            int g = block_row + i * 2 + ty;
            if (g < n_nodes) P[(size_t)g * DOUTC + c] = acc[i];
        }
    } else {
        float bv = bias[c];
        #pragma unroll
        for (int i = 0; i < 8; ++i) {
            int g = block_row + i * 2 + ty;
            if (g < n_nodes) out[(size_t)g * DOUTC + c] = acc[i] + bv;
        }
    }
}

// ---------------------------------------------------------------------------
extern "C" void kernel_launch(void* const* d_in, const int* in_sizes, int n_in,
                              void* d_out, int out_size, void* d_ws, size_t ws_size,
                              hipStream_t stream)
{
    const float* x     = (const float*)d_in[0];
    const int*   ei    = (const int*)  d_in[1];
    const float* Wl1   = (const float*)d_in[2];
    const float* Wr1   = (const float*)d_in[3];
    const float* b1    = (const float*)d_in[4];
    const float* gamma = (const float*)d_in[5];
    const float* beta  = (const float*)d_in[6];
    const float* Wl2   = (const float*)d_in[7];
    const float* Wr2   = (const float*)d_in[8];
    const float* b2    = (const float*)d_in[9];
    float*       out   = (float*)d_out;

    const int N = in_sizes[0] / DIN;      // 50000
    const int E = in_sizes[1] / 2;        // 800000

    // workspace layout: float arrays first (keeps 8B alignment for float2)
    float* ws       = (float*)d_ws;
    float* agg      = ws;                            // N*128
    float* h        = agg + (size_t)N * DIN;         // N*128
    float* P        = h + (size_t)N * DH;            // N*64
    float* bn_sum   = P + (size_t)N * DOUTC;         // 128
    float* bn_sumsq = bn_sum + DH;                   // 128
    int* deg        = (int*)(bn_sumsq + DH);         // N
    int* fill       = deg + N;                       // N
    int* cursor     = fill + N;                      // 1
    int* row_start  = cursor + 1;                    // N
    int* sorted_src = row_start + N;                 // E

    // zero: bn_sum, bn_sumsq, deg, fill, cursor (contiguous)
    hipMemsetAsync(bn_sum, 0, (2 * DH + 2 * (size_t)N + 1) * sizeof(float), stream);

    dim3 blk(256);
    const int edge_blocks = (E + 255) / 256;
    const int node_blocks = (N + 255) / 256;
    const int wave_blocks = (N + 3) / 4;       // 4 waves (nodes) per block
    const int row_blocks  = (N + 15) / 16;

    // ---- CSR build (by dst) ----
    hist_kernel<<<edge_blocks, blk, 0, stream>>>(ei, deg, E);
    alloc_kernel<<<node_blocks, blk, 0, stream>>>(deg, row_start, cursor, N);
    bucket_kernel<<<edge_blocks, blk, 0, stream>>>(ei, row_start, fill, sorted_src, E);

    // ---- layer 1 ----
    agg_gather128<<<wave_blocks, blk, 0, stream>>>(row_start, deg, sorted_src,
                                                   x, agg, N);
    gemm1_kernel<<<row_blocks, blk, 0, stream>>>(x, agg, Wl1, Wr1, b1,
                                                 h, bn_sum, bn_sumsq, N);
    int bn_blocks = ((size_t)N * DH + 255) / 256;
    bn_relu_kernel<<<bn_blocks, blk, 0, stream>>>(h, gamma, beta, bn_sum, bn_sumsq, N);

    // ---- layer 2 (project first: mean_agg(h)@Wl2 == mean_agg(h@Wl2)) ----
    gemm2p_kernel<<<row_blocks, blk, 0, stream>>>(h, Wl2, Wr2, b2, P, out, N);
    agg_gather64_add<<<wave_blocks, blk, 0, stream>>>(row_start, deg, sorted_src,
                                                      P, out, N);
}

// Round 4
// 442.940 us; speedup vs baseline: 6.7272x; 1.0293x over previous
//
#include <hip/hip_runtime.h>
#include <hip/hip_bf16.h>

#define DIN   128
#define DH    128
#define DOUTC 64
#define BN_EPS 1e-5f

// ---------------------------------------------------------------------------
// CSR build, step 1: degree histogram over dst (int atomics).
// ---------------------------------------------------------------------------
__global__ __launch_bounds__(256) void hist_kernel(
    const int* __restrict__ ei, int* __restrict__ deg, int E)
{
    int e = blockIdx.x * 256 + threadIdx.x;
    if (e < E) atomicAdd(&deg[ei[E + e]], 1);
}

// ---------------------------------------------------------------------------
// CSR build, step 2: slice allocation via wave-scan + 1 atomic/wave.
// ---------------------------------------------------------------------------
__global__ __launch_bounds__(256) void alloc_kernel(
    const int* __restrict__ deg, int* __restrict__ row_start,
    int* __restrict__ cursor, int n)
{
    int i    = blockIdx.x * 256 + threadIdx.x;
    int lane = threadIdx.x & 63;
    int v = (i < n) ? deg[i] : 0;
    int inc = v;
    #pragma unroll
    for (int off = 1; off < 64; off <<= 1) {
        int t = __shfl_up(inc, off, 64);
        if (lane >= off) inc += t;
    }
    int total = __shfl(inc, 63, 64);
    int base = 0;
    if (lane == 63) base = atomicAdd(cursor, total);
    base = __shfl(base, 63, 64);
    if (i < n) row_start[i] = base + inc - v;
}

// ---------------------------------------------------------------------------
// CSR build, step 3: bucket src ids into per-dst slices.
// ---------------------------------------------------------------------------
__global__ __launch_bounds__(256) void bucket_kernel(
    const int* __restrict__ ei, const int* __restrict__ row_start,
    int* __restrict__ fill, int* __restrict__ sorted_src, int E)
{
    int e = blockIdx.x * 256 + threadIdx.x;
    if (e >= E) return;
    int s = ei[e];
    int d = ei[E + e];
    int pos = row_start[d] + atomicAdd(&fill[d], 1);
    sorted_src[pos] = s;
}

// ---------------------------------------------------------------------------
// Gather-mean, 128-wide rows. One wave per node; half-waves process 2
// neighbors per iteration with float4 loads; shfl_xor(32) combine.
// ALL __shfl calls are full-wave (tail predicates are wave-uniform; only the
// load/accumulate is lane-predicated) — ds_bpermute from an EXEC-masked-off
// lane returns undefined data, which broke round 3.
// ---------------------------------------------------------------------------
__global__ __launch_bounds__(256) void agg_gather128(
    const int* __restrict__ row_start, const int* __restrict__ deg,
    const int* __restrict__ sorted_src, const float* __restrict__ feat,
    float* __restrict__ agg, int n)
{
    int wave = (blockIdx.x * 256 + threadIdx.x) >> 6;
    int lane = threadIdx.x & 63;
    if (wave >= n) return;
    int sub  = lane & 31;       // float4 column (32*16B = 512B row)
    int half = lane >> 5;       // which of 2 concurrent neighbors
    int base = row_start[wave];
    int d    = deg[wave];
    float4 acc = {0.f, 0.f, 0.f, 0.f};
    for (int k0 = 0; k0 < d; k0 += 64) {
        int idx = k0 + lane;
        int mys = (idx < d) ? sorted_src[base + idx] : 0;
        int kmax  = min(64, d - k0);   // wave-uniform
        int keven = kmax & ~1;
        for (int k = 0; k < keven; k += 2) {
            int s = __shfl(mys, k + half, 64);     // full wave
            float4 v = ((const float4*)(feat + (size_t)s * DIN))[sub];
            acc.x += v.x; acc.y += v.y; acc.z += v.z; acc.w += v.w;
        }
        if (kmax & 1) {                            // wave-uniform branch
            int s = __shfl(mys, kmax - 1, 64);     // full wave
            if (half == 0) {                       // lane-predicated add only
                float4 v = ((const float4*)(feat + (size_t)s * DIN))[sub];
                acc.x += v.x; acc.y += v.y; acc.z += v.z; acc.w += v.w;
            }
        }
    }
    acc.x += __shfl_xor(acc.x, 32, 64);
    acc.y += __shfl_xor(acc.y, 32, 64);
    acc.z += __shfl_xor(acc.z, 32, 64);
    acc.w += __shfl_xor(acc.w, 32, 64);
    if (half == 0) {
        float inv = 1.0f / fmaxf((float)d, 1.0f);
        float4 o = {acc.x * inv, acc.y * inv, acc.z * inv, acc.w * inv};
        ((float4*)(agg + (size_t)wave * DIN))[sub] = o;
    }
}

// ---------------------------------------------------------------------------
// Gather-mean, 64-wide (projected layer-2 features), accumulating into out.
// Quarter-waves process 4 neighbors/iteration; full-wave shfls (see above).
// ---------------------------------------------------------------------------
__global__ __launch_bounds__(256) void agg_gather64_add(
    const int* __restrict__ row_start, const int* __restrict__ deg,
    const int* __restrict__ sorted_src, const float* __restrict__ P,
    float* __restrict__ out, int n)
{
    int wave = (blockIdx.x * 256 + threadIdx.x) >> 6;
    int lane = threadIdx.x & 63;
    if (wave >= n) return;
    int sub  = lane & 15;       // float4 column (16*16B = 256B row)
    int quad = lane >> 4;       // which of 4 concurrent neighbors
    int base = row_start[wave];
    int d    = deg[wave];
    float4 acc = {0.f, 0.f, 0.f, 0.f};
    for (int k0 = 0; k0 < d; k0 += 64) {
        int idx = k0 + lane;
        int mys = (idx < d) ? sorted_src[base + idx] : 0;
        int kmax = min(64, d - k0);    // wave-uniform
        int kq   = kmax & ~3;
        for (int k = 0; k < kq; k += 4) {
            int s = __shfl(mys, k + quad, 64);     // full wave
            float4 v = ((const float4*)(P + (size_t)s * DOUTC))[sub];
            acc.x += v.x; acc.y += v.y; acc.z += v.z; acc.w += v.w;
        }
        int rem = kmax - kq;           // wave-uniform, 0..3
        if (rem) {
            int srcl = kq + quad;
            if (srcl >= kmax) srcl = kmax - 1;     // clamp into valid range
            int s = __shfl(mys, srcl, 64);         // full wave
            if (quad < rem) {                      // lane-predicated add only
                float4 v = ((const float4*)(P + (size_t)s * DOUTC))[sub];
                acc.x += v.x; acc.y += v.y; acc.z += v.z; acc.w += v.w;
            }
        }
    }
    acc.x += __shfl_xor(acc.x, 32, 64);
    acc.y += __shfl_xor(acc.y, 32, 64);
    acc.z += __shfl_xor(acc.z, 32, 64);
    acc.w += __shfl_xor(acc.w, 32, 64);
    acc.x += __shfl_xor(acc.x, 16, 64);
    acc.y += __shfl_xor(acc.y, 16, 64);
    acc.z += __shfl_xor(acc.z, 16, 64);
    acc.w += __shfl_xor(acc.w, 16, 64);
    if (quad == 0) {
        float inv = 1.0f / fmaxf((float)d, 1.0f);
        float4* op = (float4*)(out + (size_t)wave * DOUTC) + sub;
        float4 cur = *op;
        cur.x += acc.x * inv; cur.y += acc.y * inv;
        cur.z += acc.z * inv; cur.w += acc.w * inv;
        *op = cur;
    }
}

// ---------------------------------------------------------------------------
// GEMM1: h = agg @ Wl1 + x @ Wr1 + b1   [N,128]  (agg pre-meaned)
// 64 rows x 128 cols per block, 256 threads; each thread 8 rows x 4 cols.
// LDS [64][256] = 64 KB: writes stride-1 (no conflict), reads broadcast (free).
// ---------------------------------------------------------------------------
__global__ __launch_bounds__(256) void gemm1_kernel(
    const float* __restrict__ x, const float* __restrict__ agg,
    const float* __restrict__ Wl, const float* __restrict__ Wr,
    const float* __restrict__ bias,
    float* __restrict__ h, int n_nodes)
{
    __shared__ float in_lds[64][256];
    const int block_row = blockIdx.x * 64;
    const int tid = threadIdx.x;

    #pragma unroll
    for (int i = 0; i < 16; ++i) {
        int idx = tid + i * 256;       // float4 index
        int r   = idx >> 6;            // 0..63
        int c4  = idx & 63;            // float4 col 0..63 (256 floats)
        int g   = block_row + r;
        float4 v = {0.f, 0.f, 0.f, 0.f};
        if (g < n_nodes) {
            v = (c4 < 32) ? ((const float4*)(agg + (size_t)g * DIN))[c4]
                          : ((const float4*)(x   + (size_t)g * DIN))[c4 - 32];
        }
        ((float4*)&in_lds[r][0])[c4] = v;
    }
    __syncthreads();

    const int tx = tid & 31;    // col quad: cols tx*4 .. tx*4+3
    const int ty = tid >> 5;    // row group: rows ty*8 .. ty*8+7
    float4 acc[8];
    #pragma unroll
    for (int i = 0; i < 8; ++i) acc[i] = (float4){0.f, 0.f, 0.f, 0.f};

    const float* Wlp = Wl + tx * 4;
    for (int k = 0; k < DIN; k += 2) {
        float4 w0 = *(const float4*)(Wlp + (size_t)k * DH);
        float4 w1 = *(const float4*)(Wlp + (size_t)(k + 1) * DH);
        #pragma unroll
        for (int i = 0; i < 8; ++i) {
            float2 a = *(const float2*)&in_lds[ty * 8 + i][k];
            acc[i].x += a.x * w0.x + a.y * w1.x;
            acc[i].y += a.x * w0.y + a.y * w1.y;
            acc[i].z += a.x * w0.z + a.y * w1.z;
            acc[i].w += a.x * w0.w + a.y * w1.w;
        }
    }
    const float* Wrp = Wr + tx * 4;
    for (int k = 0; k < DIN; k += 2) {
        float4 w0 = *(const float4*)(Wrp + (size_t)k * DH);
        float4 w1 = *(const float4*)(Wrp + (size_t)(k + 1) * DH);
        #pragma unroll
        for (int i = 0; i < 8; ++i) {
            float2 a = *(const float2*)&in_lds[ty * 8 + i][DIN + k];
            acc[i].x += a.x * w0.x + a.y * w1.x;
            acc[i].y += a.x * w0.y + a.y * w1.y;
            acc[i].z += a.x * w0.z + a.y * w1.z;
            acc[i].w += a.x * w0.w + a.y * w1.w;
        }
    }

    float4 bv = *(const float4*)(bias + tx * 4);
    #pragma unroll
    for (int i = 0; i < 8; ++i) {
        int g = block_row + ty * 8 + i;
        if (g < n_nodes) {
            float4 o = {acc[i].x + bv.x, acc[i].y + bv.y,
                        acc[i].z + bv.z, acc[i].w + bv.w};
            ((float4*)(h + (size_t)g * DH))[tx] = o;
        }
    }
}

// ---------------------------------------------------------------------------
// BN stats: per-column sum & sumsq over h. 128 blocks -> 128 atomics/col.
// ---------------------------------------------------------------------------
__global__ __launch_bounds__(256) void bn_stats_kernel(
    const float* __restrict__ h,
    float* __restrict__ bn_sum, float* __restrict__ bn_sumsq, int n_nodes)
{
    __shared__ float rsum[2][128];
    __shared__ float rsq[2][128];
    int col = threadIdx.x & 127;
    int rg  = threadIdx.x >> 7;        // 0/1
    float psum = 0.f, psq = 0.f;
    for (int r = blockIdx.x * 2 + rg; r < n_nodes; r += gridDim.x * 2) {
        float v = h[(size_t)r * DH + col];
        psum += v; psq += v * v;
    }
    rsum[rg][col] = psum;
    rsq[rg][col]  = psq;
    __syncthreads();
    if (rg == 0) {
        atomicAdd(&bn_sum[col],   rsum[0][col] + rsum[1][col]);
        atomicAdd(&bn_sumsq[col], rsq[0][col]  + rsq[1][col]);
    }
}

// ---------------------------------------------------------------------------
// BatchNorm (batch stats, biased var) + ReLU, in place on h.
// ---------------------------------------------------------------------------
__global__ __launch_bounds__(256) void bn_relu_kernel(
    float* __restrict__ h,
    const float* __restrict__ gamma, const float* __restrict__ beta,
    const float* __restrict__ bn_sum, const float* __restrict__ bn_sumsq,
    int n_nodes)
{
    int idx = blockIdx.x * 256 + threadIdx.x;
    int total = n_nodes * DH;
    if (idx >= total) return;
    int col = idx & (DH - 1);
    float invN = 1.0f / (float)n_nodes;
    float mu  = bn_sum[col] * invN;
    float var = bn_sumsq[col] * invN - mu * mu;
    float rs  = rsqrtf(var + BN_EPS);
    float v = (h[idx] - mu) * rs * gamma[col] + beta[col];
    h[idx] = fmaxf(v, 0.0f);
}

// ---------------------------------------------------------------------------
// GEMM2 projection: P = h @ Wl2 (cols 0..63) and out = h @ Wr2 + b2
// (cols 64..127), one [N,128]@[128,128] block-GEMM, same register blocking.
// ---------------------------------------------------------------------------
__global__ __launch_bounds__(256) void gemm2p_kernel(
    const float* __restrict__ h,
    const float* __restrict__ Wl, const float* __restrict__ Wr,
    const float* __restrict__ bias,
    float* __restrict__ P, float* __restrict__ out, int n_nodes)
{
    __shared__ float in_lds[64][128];
    const int block_row = blockIdx.x * 64;
    const int tid = threadIdx.x;

    #pragma unroll
    for (int i = 0; i < 8; ++i) {
        int idx = tid + i * 256;
        int r   = idx >> 5;            // 0..63
        int c4  = idx & 31;            // float4 col 0..31
        int g   = block_row + r;
        float4 v = {0.f, 0.f, 0.f, 0.f};
        if (g < n_nodes) v = ((const float4*)(h + (size_t)g * DH))[c4];
        ((float4*)&in_lds[r][0])[c4] = v;
    }
    __syncthreads();

    const int tx = tid & 31;    // concat col quad: cols tx*4 (0..127)
    const int ty = tid >> 5;
    const int lhalf = (tx < 16);
    const float* Wp = lhalf ? (Wl + tx * 4) : (Wr + (tx * 4 - 64));

    float4 acc[8];
    #pragma unroll
    for (int i = 0; i < 8; ++i) acc[i] = (float4){0.f, 0.f, 0.f, 0.f};

    for (int k = 0; k < DH; k += 2) {
        float4 w0 = *(const float4*)(Wp + (size_t)k * DOUTC);
        float4 w1 = *(const float4*)(Wp + (size_t)(k + 1) * DOUTC);
        #pragma unroll
        for (int i = 0; i < 8; ++i) {
            float2 a = *(const float2*)&in_lds[ty * 8 + i][k];
            acc[i].x += a.x * w0.x + a.y * w1.x;
            acc[i].y += a.x * w0.y + a.y * w1.y;
            acc[i].z += a.x * w0.z + a.y * w1.z;
            acc[i].w += a.x * w0.w + a.y * w1.w;
        }
    }

    if (lhalf) {
        #pragma unroll
        for (int i = 0; i < 8; ++i) {
            int g = block_row + ty * 8 + i;
            if (g < n_nodes)
                ((float4*)(P + (size_t)g * DOUTC))[tx] = acc[i];
        }
    } else {
        int c = tx * 4 - 64;
        float4 bv = *(const float4*)(bias + c);
        #pragma unroll
        for (int i = 0; i < 8; ++i) {
            int g = block_row + ty * 8 + i;
            if (g < n_nodes) {
                float4 o = {acc[i].x + bv.x, acc[i].y + bv.y,
                            acc[i].z + bv.z, acc[i].w + bv.w};
                *((float4*)(out + (size_t)g * DOUTC + c)) = o;
            }
        }
    }
}

// ---------------------------------------------------------------------------
extern "C" void kernel_launch(void* const* d_in, const int* in_sizes, int n_in,
                              void* d_out, int out_size, void* d_ws, size_t ws_size,
                              hipStream_t stream)
{
    const float* x     = (const float*)d_in[0];
    const int*   ei    = (const int*)  d_in[1];
    const float* Wl1   = (const float*)d_in[2];
    const float* Wr1   = (const float*)d_in[3];
    const float* b1    = (const float*)d_in[4];
    const float* gamma = (const float*)d_in[5];
    const float* beta  = (const float*)d_in[6];
    const float* Wl2   = (const float*)d_in[7];
    const float* Wr2   = (const float*)d_in[8];
    const float* b2    = (const float*)d_in[9];
    float*       out   = (float*)d_out;

    const int N = in_sizes[0] / DIN;      // 50000
    const int E = in_sizes[1] / 2;        // 800000

    // workspace layout
    float* ws       = (float*)d_ws;
    float* agg      = ws;                            // N*128
    float* h        = agg + (size_t)N * DIN;         // N*128
    float* P        = h + (size_t)N * DH;            // N*64
    float* bn_sum   = P + (size_t)N * DOUTC;         // 128
    float* bn_sumsq = bn_sum + DH;                   // 128
    int* deg        = (int*)(bn_sumsq + DH);         // N
    int* fill       = deg + N;                       // N
    int* cursor     = fill + N;                      // 1
    int* row_start  = cursor + 1;                    // N
    int* sorted_src = row_start + N;                 // E

    // zero: bn_sum, bn_sumsq, deg, fill, cursor (contiguous)
    hipMemsetAsync(bn_sum, 0, (2 * DH + 2 * (size_t)N + 1) * sizeof(float), stream);

    dim3 blk(256);
    const int edge_blocks = (E + 255) / 256;
    const int node_blocks = (N + 255) / 256;
    const int wave_blocks = (N + 3) / 4;
    const int gemm_blocks = (N + 63) / 64;

    // ---- CSR build (by dst) ----
    hist_kernel<<<edge_blocks, blk, 0, stream>>>(ei, deg, E);
    alloc_kernel<<<node_blocks, blk, 0, stream>>>(deg, row_start, cursor, N);
    bucket_kernel<<<edge_blocks, blk, 0, stream>>>(ei, row_start, fill, sorted_src, E);

    // ---- layer 1 ----
    agg_gather128<<<wave_blocks, blk, 0, stream>>>(row_start, deg, sorted_src,
                                                   x, agg, N);
    gemm1_kernel<<<gemm_blocks, blk, 0, stream>>>(x, agg, Wl1, Wr1, b1, h, N);
    bn_stats_kernel<<<128, blk, 0, stream>>>(h, bn_sum, bn_sumsq, N);
    int bn_blocks = ((size_t)N * DH + 255) / 256;
    bn_relu_kernel<<<bn_blocks, blk, 0, stream>>>(h, gamma, beta, bn_sum, bn_sumsq, N);

    // ---- layer 2 (project first: mean_agg(h)@Wl2 == mean_agg(h@Wl2)) ----
    gemm2p_kernel<<<gemm_blocks, blk, 0, stream>>>(h, Wl2, Wr2, b2, P, out, N);
    agg_gather64_add<<<wave_blocks, blk, 0, stream>>>(row_start, deg, sorted_src,
                                                      P, out, N);
}

// Round 5
// 394.761 us; speedup vs baseline: 7.5482x; 1.1220x over previous
//
#include <hip/hip_runtime.h>
#include <hip/hip_bf16.h>

#define DIN   128
#define DH    128
#define DOUTC 64
#define BN_EPS 1e-5f

// ---------------------------------------------------------------------------
// CSR build, step 1: degree histogram over dst (int atomics).
// ---------------------------------------------------------------------------
__global__ __launch_bounds__(256) void hist_kernel(
    const int* __restrict__ ei, int* __restrict__ deg, int E)
{
    int e = blockIdx.x * 256 + threadIdx.x;
    if (e < E) atomicAdd(&deg[ei[E + e]], 1);
}

// ---------------------------------------------------------------------------
// CSR build, step 2: slice allocation via wave-scan + 1 atomic/wave.
// ---------------------------------------------------------------------------
__global__ __launch_bounds__(256) void alloc_kernel(
    const int* __restrict__ deg, int* __restrict__ row_start,
    int* __restrict__ cursor, int n)
{
    int i    = blockIdx.x * 256 + threadIdx.x;
    int lane = threadIdx.x & 63;
    int v = (i < n) ? deg[i] : 0;
    int inc = v;
    #pragma unroll
    for (int off = 1; off < 64; off <<= 1) {
        int t = __shfl_up(inc, off, 64);
        if (lane >= off) inc += t;
    }
    int total = __shfl(inc, 63, 64);
    int base = 0;
    if (lane == 63) base = atomicAdd(cursor, total);
    base = __shfl(base, 63, 64);
    if (i < n) row_start[i] = base + inc - v;
}

// ---------------------------------------------------------------------------
// CSR build, step 3: bucket src ids into per-dst slices.
// ---------------------------------------------------------------------------
__global__ __launch_bounds__(256) void bucket_kernel(
    const int* __restrict__ ei, const int* __restrict__ row_start,
    int* __restrict__ fill, int* __restrict__ sorted_src, int E)
{
    int e = blockIdx.x * 256 + threadIdx.x;
    if (e >= E) return;
    int s = ei[e];
    int d = ei[E + e];
    int pos = row_start[d] + atomicAdd(&fill[d], 1);
    sorted_src[pos] = s;
}

// ---------------------------------------------------------------------------
// Gather-mean, 128-wide fp32 rows. One wave per node; half-waves process 2
// neighbors per iteration with float4 loads; shfl_xor(32) combine.
// ALL __shfl calls full-wave (tail predicates wave-uniform).
// ---------------------------------------------------------------------------
__global__ __launch_bounds__(256) void agg_gather128(
    const int* __restrict__ row_start, const int* __restrict__ deg,
    const int* __restrict__ sorted_src, const float* __restrict__ feat,
    float* __restrict__ agg, int n)
{
    int wave = (blockIdx.x * 256 + threadIdx.x) >> 6;
    int lane = threadIdx.x & 63;
    if (wave >= n) return;
    int sub  = lane & 31;
    int half = lane >> 5;
    int base = row_start[wave];
    int d    = deg[wave];
    float4 acc = {0.f, 0.f, 0.f, 0.f};
    for (int k0 = 0; k0 < d; k0 += 64) {
        int idx = k0 + lane;
        int mys = (idx < d) ? sorted_src[base + idx] : 0;
        int kmax  = min(64, d - k0);   // wave-uniform
        int keven = kmax & ~1;
        for (int k = 0; k < keven; k += 2) {
            int s = __shfl(mys, k + half, 64);
            float4 v = ((const float4*)(feat + (size_t)s * DIN))[sub];
            acc.x += v.x; acc.y += v.y; acc.z += v.z; acc.w += v.w;
        }
        if (kmax & 1) {
            int s = __shfl(mys, kmax - 1, 64);     // full wave
            if (half == 0) {
                float4 v = ((const float4*)(feat + (size_t)s * DIN))[sub];
                acc.x += v.x; acc.y += v.y; acc.z += v.z; acc.w += v.w;
            }
        }
    }
    acc.x += __shfl_xor(acc.x, 32, 64);
    acc.y += __shfl_xor(acc.y, 32, 64);
    acc.z += __shfl_xor(acc.z, 32, 64);
    acc.w += __shfl_xor(acc.w, 32, 64);
    if (half == 0) {
        float inv = 1.0f / fmaxf((float)d, 1.0f);
        float4 o = {acc.x * inv, acc.y * inv, acc.z * inv, acc.w * inv};
        ((float4*)(agg + (size_t)wave * DIN))[sub] = o;
    }
}

// ---------------------------------------------------------------------------
// Gather-mean over bf16 P rows (64 cols = 128 B), accumulating into out.
// 8 lanes x 16 B per neighbor -> 8 neighbors concurrent per wave.
// fp32 accumulate; 3 shfl_xor rounds (32,16,8) combine; full-wave shfls.
// ---------------------------------------------------------------------------
__global__ __launch_bounds__(256) void agg_gather64_add(
    const int* __restrict__ row_start, const int* __restrict__ deg,
    const int* __restrict__ sorted_src, const __hip_bfloat16* __restrict__ P,
    float* __restrict__ out, int n)
{
    int wave = (blockIdx.x * 256 + threadIdx.x) >> 6;
    int lane = threadIdx.x & 63;
    if (wave >= n) return;
    int sub = lane & 7;         // 16B chunk of the 128B row
    int oct = lane >> 3;        // which of 8 concurrent neighbors
    int base = row_start[wave];
    int d    = deg[wave];
    float acc[8];
    #pragma unroll
    for (int j = 0; j < 8; ++j) acc[j] = 0.f;

    for (int k0 = 0; k0 < d; k0 += 64) {
        int idx = k0 + lane;
        int mys = (idx < d) ? sorted_src[base + idx] : 0;
        int kmax = min(64, d - k0);    // wave-uniform
        int ko   = kmax & ~7;
        for (int k = 0; k < ko; k += 8) {
            int s = __shfl(mys, k + oct, 64);      // full wave
            float4 raw = ((const float4*)(P + (size_t)s * DOUTC))[sub];
            const unsigned short* u = (const unsigned short*)&raw;
            #pragma unroll
            for (int j = 0; j < 8; ++j)
                acc[j] += __uint_as_float(((unsigned int)u[j]) << 16);
        }
        int rem = kmax - ko;           // wave-uniform, 0..7
        if (rem) {
            int srcl = ko + oct;
            if (srcl >= kmax) srcl = kmax - 1;     // clamp into valid range
            int s = __shfl(mys, srcl, 64);         // full wave
            if (oct < rem) {                       // lane-predicated add only
                float4 raw = ((const float4*)(P + (size_t)s * DOUTC))[sub];
                const unsigned short* u = (const unsigned short*)&raw;
                #pragma unroll
                for (int j = 0; j < 8; ++j)
                    acc[j] += __uint_as_float(((unsigned int)u[j]) << 16);
            }
        }
    }
    #pragma unroll
    for (int j = 0; j < 8; ++j) {
        acc[j] += __shfl_xor(acc[j], 32, 64);
        acc[j] += __shfl_xor(acc[j], 16, 64);
        acc[j] += __shfl_xor(acc[j],  8, 64);
    }
    if (oct == 0) {
        float inv = 1.0f / fmaxf((float)d, 1.0f);
        float* op = out + (size_t)wave * DOUTC + sub * 8;
        float4 c0 = *(float4*)op;
        float4 c1 = *((float4*)op + 1);
        c0.x += acc[0] * inv; c0.y += acc[1] * inv;
        c0.z += acc[2] * inv; c0.w += acc[3] * inv;
        c1.x += acc[4] * inv; c1.y += acc[5] * inv;
        c1.z += acc[6] * inv; c1.w += acc[7] * inv;
        *(float4*)op = c0;
        *((float4*)op + 1) = c1;
    }
}

// ---------------------------------------------------------------------------
// GEMM1: h = agg @ Wl1 + x @ Wr1 + b1, + fused BN sum/sumsq partials.
// Two-phase K (agg then x) reusing ONE 64x128 LDS tile (32 KB -> 5 blocks/CU,
// vs round-4's 64 KB tile at 2 blocks/CU which stalled at 40% VALUBusy).
// Thread = 8 rows x 4 cols. BN reduction overlays the tile via union.
// ---------------------------------------------------------------------------
__global__ __launch_bounds__(256) void gemm1_kernel(
    const float* __restrict__ x, const float* __restrict__ agg,
    const float* __restrict__ Wl, const float* __restrict__ Wr,
    const float* __restrict__ bias,
    float* __restrict__ h,
    float* __restrict__ bn_sum, float* __restrict__ bn_sumsq,
    int n_nodes)
{
    __shared__ union {
        float in[64][128];
        float red[2][8][128];   // [sum/sq][ty][col]
    } sm;

    const int block_row = blockIdx.x * 64;
    const int tid = threadIdx.x;
    const int tx = tid & 31;    // col quad: cols tx*4 .. tx*4+3
    const int ty = tid >> 5;    // row group: rows ty*8 .. ty*8+7

    float4 acc[8];
    #pragma unroll
    for (int i = 0; i < 8; ++i) acc[i] = (float4){0.f, 0.f, 0.f, 0.f};

    // ---- phase 1: agg tile vs Wl ----
    #pragma unroll
    for (int i = 0; i < 8; ++i) {
        int idx = tid + i * 256;       // float4 index 0..2047
        int r   = idx >> 5;
        int c4  = idx & 31;
        int g   = block_row + r;
        float4 v = {0.f, 0.f, 0.f, 0.f};
        if (g < n_nodes) v = ((const float4*)(agg + (size_t)g * DIN))[c4];
        ((float4*)&sm.in[r][0])[c4] = v;
    }
    __syncthreads();

    const float* Wlp = Wl + tx * 4;
    #pragma unroll 4
    for (int k = 0; k < DIN; k += 2) {
        float4 w0 = *(const float4*)(Wlp + (size_t)k * DH);
        float4 w1 = *(const float4*)(Wlp + (size_t)(k + 1) * DH);
        #pragma unroll
        for (int i = 0; i < 8; ++i) {
            float2 a = *(const float2*)&sm.in[ty * 8 + i][k];
            acc[i].x += a.x * w0.x + a.y * w1.x;
            acc[i].y += a.x * w0.y + a.y * w1.y;
            acc[i].z += a.x * w0.z + a.y * w1.z;
            acc[i].w += a.x * w0.w + a.y * w1.w;
        }
    }
    __syncthreads();

    // ---- phase 2: x tile vs Wr ----
    #pragma unroll
    for (int i = 0; i < 8; ++i) {
        int idx = tid + i * 256;
        int r   = idx >> 5;
        int c4  = idx & 31;
        int g   = block_row + r;
        float4 v = {0.f, 0.f, 0.f, 0.f};
        if (g < n_nodes) v = ((const float4*)(x + (size_t)g * DIN))[c4];
        ((float4*)&sm.in[r][0])[c4] = v;
    }
    __syncthreads();

    const float* Wrp = Wr + tx * 4;
    #pragma unroll 4
    for (int k = 0; k < DIN; k += 2) {
        float4 w0 = *(const float4*)(Wrp + (size_t)k * DH);
        float4 w1 = *(const float4*)(Wrp + (size_t)(k + 1) * DH);
        #pragma unroll
        for (int i = 0; i < 8; ++i) {
            float2 a = *(const float2*)&sm.in[ty * 8 + i][k];
            acc[i].x += a.x * w0.x + a.y * w1.x;
            acc[i].y += a.x * w0.y + a.y * w1.y;
            acc[i].z += a.x * w0.z + a.y * w1.z;
            acc[i].w += a.x * w0.w + a.y * w1.w;
        }
    }

    // ---- epilogue: bias, store h, BN partials ----
    float4 bv = *(const float4*)(bias + tx * 4);
    float4 psum = {0.f, 0.f, 0.f, 0.f};
    float4 psq  = {0.f, 0.f, 0.f, 0.f};
    #pragma unroll
    for (int i = 0; i < 8; ++i) {
        int g = block_row + ty * 8 + i;
        float4 o = {acc[i].x + bv.x, acc[i].y + bv.y,
                    acc[i].z + bv.z, acc[i].w + bv.w};
        if (g < n_nodes) {
            ((float4*)(h + (size_t)g * DH))[tx] = o;
            psum.x += o.x; psum.y += o.y; psum.z += o.z; psum.w += o.w;
            psq.x += o.x * o.x; psq.y += o.y * o.y;
            psq.z += o.z * o.z; psq.w += o.w * o.w;
        }
    }
    __syncthreads();                 // done with sm.in; reuse as sm.red
    ((float4*)&sm.red[0][ty][0])[tx] = psum;
    ((float4*)&sm.red[1][ty][0])[tx] = psq;
    __syncthreads();
    if (tid < 128) {
        float s = 0.f, q = 0.f;
        #pragma unroll
        for (int g = 0; g < 8; ++g) {
            s += sm.red[0][g][tid];
            q += sm.red[1][g][tid];
        }
        atomicAdd(&bn_sum[tid], s);
        atomicAdd(&bn_sumsq[tid], q);
    }
}

// ---------------------------------------------------------------------------
// BN finalize: scale = gamma*rsqrt(var+eps), shift = beta - mu*scale.
// ---------------------------------------------------------------------------
__global__ void bn_finalize_kernel(
    const float* __restrict__ bn_sum, const float* __restrict__ bn_sumsq,
    const float* __restrict__ gamma, const float* __restrict__ beta,
    float* __restrict__ scale, float* __restrict__ shift, int n_nodes)
{
    int c = threadIdx.x;
    if (c >= DH) return;
    float invN = 1.0f / (float)n_nodes;
    float mu  = bn_sum[c] * invN;
    float var = bn_sumsq[c] * invN - mu * mu;
    float sc  = gamma[c] * rsqrtf(var + BN_EPS);
    scale[c] = sc;
    shift[c] = beta[c] - mu * sc;
}

// ---------------------------------------------------------------------------
// GEMM2 projection with fused BN+ReLU on load:
// a = relu(h*scale+shift); P = a @ Wl2 (bf16), out = a @ Wr2 + b2 (fp32).
// ---------------------------------------------------------------------------
__global__ __launch_bounds__(256) void gemm2p_kernel(
    const float* __restrict__ h,
    const float* __restrict__ scale, const float* __restrict__ shift,
    const float* __restrict__ Wl, const float* __restrict__ Wr,
    const float* __restrict__ bias,
    __hip_bfloat16* __restrict__ P, float* __restrict__ out, int n_nodes)
{
    __shared__ float in_lds[64][128];
    const int block_row = blockIdx.x * 64;
    const int tid = threadIdx.x;

    #pragma unroll
    for (int i = 0; i < 8; ++i) {
        int idx = tid + i * 256;
        int r   = idx >> 5;
        int c4  = idx & 31;
        int g   = block_row + r;
        float4 v = {0.f, 0.f, 0.f, 0.f};
        if (g < n_nodes) {
            float4 raw = ((const float4*)(h + (size_t)g * DH))[c4];
            float4 sc = ((const float4*)scale)[c4];
            float4 sh = ((const float4*)shift)[c4];
            v.x = fmaxf(raw.x * sc.x + sh.x, 0.f);
            v.y = fmaxf(raw.y * sc.y + sh.y, 0.f);
            v.z = fmaxf(raw.z * sc.z + sh.z, 0.f);
            v.w = fmaxf(raw.w * sc.w + sh.w, 0.f);
        }
        ((float4*)&in_lds[r][0])[c4] = v;
    }
    __syncthreads();

    const int tx = tid & 31;    // concat col quad (0..127 cols)
    const int ty = tid >> 5;
    const int lhalf = (tx < 16);
    const float* Wp = lhalf ? (Wl + tx * 4) : (Wr + (tx * 4 - 64));

    float4 acc[8];
    #pragma unroll
    for (int i = 0; i < 8; ++i) acc[i] = (float4){0.f, 0.f, 0.f, 0.f};

    #pragma unroll 4
    for (int k = 0; k < DH; k += 2) {
        float4 w0 = *(const float4*)(Wp + (size_t)k * DOUTC);
        float4 w1 = *(const float4*)(Wp + (size_t)(k + 1) * DOUTC);
        #pragma unroll
        for (int i = 0; i < 8; ++i) {
            float2 a = *(const float2*)&in_lds[ty * 8 + i][k];
            acc[i].x += a.x * w0.x + a.y * w1.x;
            acc[i].y += a.x * w0.y + a.y * w1.y;
            acc[i].z += a.x * w0.z + a.y * w1.z;
            acc[i].w += a.x * w0.w + a.y * w1.w;
        }
    }

    if (lhalf) {
        #pragma unroll
        for (int i = 0; i < 8; ++i) {
            int g = block_row + ty * 8 + i;
            if (g < n_nodes) {
                __hip_bfloat16 tmp[4];
                tmp[0] = __float2bfloat16(acc[i].x);
                tmp[1] = __float2bfloat16(acc[i].y);
                tmp[2] = __float2bfloat16(acc[i].z);
                tmp[3] = __float2bfloat16(acc[i].w);
                *(uint2*)(P + (size_t)g * DOUTC + tx * 4) = *(uint2*)tmp;
            }
        }
    } else {
        int c = tx * 4 - 64;
        float4 bv = *(const float4*)(bias + c);
        #pragma unroll
        for (int i = 0; i < 8; ++i) {
            int g = block_row + ty * 8 + i;
            if (g < n_nodes) {
                float4 o = {acc[i].x + bv.x, acc[i].y + bv.y,
                            acc[i].z + bv.z, acc[i].w + bv.w};
                *((float4*)(out + (size_t)g * DOUTC + c)) = o;
            }
        }
    }
}

// ---------------------------------------------------------------------------
extern "C" void kernel_launch(void* const* d_in, const int* in_sizes, int n_in,
                              void* d_out, int out_size, void* d_ws, size_t ws_size,
                              hipStream_t stream)
{
    const float* x     = (const float*)d_in[0];
    const int*   ei    = (const int*)  d_in[1];
    const float* Wl1   = (const float*)d_in[2];
    const float* Wr1   = (const float*)d_in[3];
    const float* b1    = (const float*)d_in[4];
    const float* gamma = (const float*)d_in[5];
    const float* beta  = (const float*)d_in[6];
    const float* Wl2   = (const float*)d_in[7];
    const float* Wr2   = (const float*)d_in[8];
    const float* b2    = (const float*)d_in[9];
    float*       out   = (float*)d_out;

    const int N = in_sizes[0] / DIN;      // 50000
    const int E = in_sizes[1] / 2;        // 800000

    // workspace layout
    float* ws       = (float*)d_ws;
    float* agg      = ws;                            // N*128 f32
    float* h        = agg + (size_t)N * DIN;         // N*128 f32
    __hip_bfloat16* P = (__hip_bfloat16*)(h + (size_t)N * DH);  // N*64 bf16
    float* bn_sum   = (float*)(P + (size_t)N * DOUTC);   // 128
    float* bn_sumsq = bn_sum + DH;                   // 128
    float* scale    = bn_sumsq + DH;                 // 128
    float* shift    = scale + DH;                    // 128
    int* deg        = (int*)(shift + DH);            // N
    int* fill       = deg + N;                       // N
    int* cursor     = fill + N;                      // 1
    int* row_start  = cursor + 1;                    // N
    int* sorted_src = row_start + N;                 // E

    // zero: bn_sum..cursor (scale/shift zeroed harmlessly, overwritten later)
    hipMemsetAsync(bn_sum, 0, (4 * DH + 2 * (size_t)N + 1) * sizeof(float), stream);

    dim3 blk(256);
    const int edge_blocks = (E + 255) / 256;
    const int node_blocks = (N + 255) / 256;
    const int wave_blocks = (N + 3) / 4;
    const int gemm_blocks = (N + 63) / 64;

    // ---- CSR build (by dst) ----
    hist_kernel<<<edge_blocks, blk, 0, stream>>>(ei, deg, E);
    alloc_kernel<<<node_blocks, blk, 0, stream>>>(deg, row_start, cursor, N);
    bucket_kernel<<<edge_blocks, blk, 0, stream>>>(ei, row_start, fill, sorted_src, E);

    // ---- layer 1 ----
    agg_gather128<<<wave_blocks, blk, 0, stream>>>(row_start, deg, sorted_src,
                                                   x, agg, N);
    gemm1_kernel<<<gemm_blocks, blk, 0, stream>>>(x, agg, Wl1, Wr1, b1, h,
                                                  bn_sum, bn_sumsq, N);
    bn_finalize_kernel<<<1, 128, 0, stream>>>(bn_sum, bn_sumsq, gamma, beta,
                                              scale, shift, N);

    // ---- layer 2 (BN+ReLU fused into load; P bf16; project-then-gather) ----
    gemm2p_kernel<<<gemm_blocks, blk, 0, stream>>>(h, scale, shift,
                                                   Wl2, Wr2, b2, P, out, N);
    agg_gather64_add<<<wave_blocks, blk, 0, stream>>>(row_start, deg, sorted_src,
                                                      P, out, N);
}

// Round 6
// 304.269 us; speedup vs baseline: 9.7931x; 1.2974x over previous
//
#include <hip/hip_runtime.h>
#include <hip/hip_bf16.h>

#define DIN   128
#define DH    128
#define DOUTC 64
#define BN_EPS 1e-5f

typedef __attribute__((ext_vector_type(8))) short bf16x8;
typedef __attribute__((ext_vector_type(4))) float f32x4;

__device__ inline unsigned short f2bf(float f) {
    __hip_bfloat16 b = __float2bfloat16(f);
    return *reinterpret_cast<unsigned short*>(&b);
}
__device__ inline float bf2f(unsigned short u) {
    return __uint_as_float(((unsigned int)u) << 16);
}

// ---------------------------------------------------------------------------
// fp32 -> bf16 row convert (8 elements / thread).
// ---------------------------------------------------------------------------
__global__ __launch_bounds__(256) void cvt_bf16_kernel(
    const float* __restrict__ src, unsigned short* __restrict__ dst, int total8)
{
    int i = blockIdx.x * 256 + threadIdx.x;
    if (i >= total8) return;
    float4 a = ((const float4*)src)[2 * i];
    float4 b = ((const float4*)src)[2 * i + 1];
    unsigned short t[8];
    t[0]=f2bf(a.x); t[1]=f2bf(a.y); t[2]=f2bf(a.z); t[3]=f2bf(a.w);
    t[4]=f2bf(b.x); t[5]=f2bf(b.y); t[6]=f2bf(b.z); t[7]=f2bf(b.w);
    *(uint4*)(dst + (size_t)i * 8) = *(uint4*)t;
}

// ---------------------------------------------------------------------------
// Pack a K x 128 fp32 weight into B-fragment order (bf16) for 16x16x32 MFMA:
// dst[ (k/32 * 8 + c/16)*512 + ((k/8)&3)*128 + (c&15)*8 + (k&7) ] = W[k][c]
// so a wave's frag load (lane reads 8 bf16 at tile*512 + lane*8) yields
// B[k = quad*8+j][n = lane&15].
// ---------------------------------------------------------------------------
__global__ __launch_bounds__(256) void pack_w_kernel(
    const float* __restrict__ W, unsigned short* __restrict__ dst, int K)
{
    int idx = blockIdx.x * 256 + threadIdx.x;
    if (idx >= K * 128) return;
    int k = idx >> 7, c = idx & 127;
    int d = ((k >> 5) * 8 + (c >> 4)) * 512 + ((k >> 3) & 3) * 128 + (c & 15) * 8 + (k & 7);
    dst[d] = f2bf(W[idx]);
}

// Same, but source columns are the concatenation [Wl (64) | Wr (64)].
__global__ __launch_bounds__(256) void pack_wcat_kernel(
    const float* __restrict__ Wl, const float* __restrict__ Wr,
    unsigned short* __restrict__ dst, int K)
{
    int idx = blockIdx.x * 256 + threadIdx.x;
    if (idx >= K * 128) return;
    int k = idx >> 7, c = idx & 127;
    float v = (c < 64) ? Wl[k * 64 + c] : Wr[k * 64 + (c - 64)];
    int d = ((k >> 5) * 8 + (c >> 4)) * 512 + ((k >> 3) & 3) * 128 + (c & 15) * 8 + (k & 7);
    dst[d] = f2bf(v);
}

// ---------------------------------------------------------------------------
// CSR build.
// ---------------------------------------------------------------------------
__global__ __launch_bounds__(256) void hist_kernel(
    const int* __restrict__ ei, int* __restrict__ deg, int E)
{
    int e = blockIdx.x * 256 + threadIdx.x;
    if (e < E) atomicAdd(&deg[ei[E + e]], 1);
}

__global__ __launch_bounds__(256) void alloc_kernel(
    const int* __restrict__ deg, int* __restrict__ row_start,
    int* __restrict__ cursor, int n)
{
    int i    = blockIdx.x * 256 + threadIdx.x;
    int lane = threadIdx.x & 63;
    int v = (i < n) ? deg[i] : 0;
    int inc = v;
    #pragma unroll
    for (int off = 1; off < 64; off <<= 1) {
        int t = __shfl_up(inc, off, 64);
        if (lane >= off) inc += t;
    }
    int total = __shfl(inc, 63, 64);
    int base = 0;
    if (lane == 63) base = atomicAdd(cursor, total);
    base = __shfl(base, 63, 64);
    if (i < n) row_start[i] = base + inc - v;
}

__global__ __launch_bounds__(256) void bucket_kernel(
    const int* __restrict__ ei, const int* __restrict__ row_start,
    int* __restrict__ fill, int* __restrict__ sorted_src, int E)
{
    int e = blockIdx.x * 256 + threadIdx.x;
    if (e >= E) return;
    int s = ei[e];
    int d = ei[E + e];
    int pos = row_start[d] + atomicAdd(&fill[d], 1);
    sorted_src[pos] = s;
}

// ---------------------------------------------------------------------------
// Gather-mean over bf16 x rows (128 cols = 256 B). One wave per node;
// 16 lanes x 16 B per neighbor -> 4 neighbors concurrent. fp32 accumulate,
// bf16 store. All __shfl full-wave (tail predicates wave-uniform).
// ---------------------------------------------------------------------------
__global__ __launch_bounds__(256) void agg_gather128(
    const int* __restrict__ row_start, const int* __restrict__ deg,
    const int* __restrict__ sorted_src, const unsigned short* __restrict__ xb,
    unsigned short* __restrict__ aggb, int n)
{
    int wave = (blockIdx.x * 256 + threadIdx.x) >> 6;
    int lane = threadIdx.x & 63;
    if (wave >= n) return;
    int sub  = lane & 15;      // 16B chunk of 256B row
    int quad = lane >> 4;      // which of 4 concurrent neighbors
    int base = row_start[wave];
    int d    = deg[wave];
    float acc[8];
    #pragma unroll
    for (int j = 0; j < 8; ++j) acc[j] = 0.f;

    for (int k0 = 0; k0 < d; k0 += 64) {
        int idx = k0 + lane;
        int mys = (idx < d) ? sorted_src[base + idx] : 0;
        int kmax = min(64, d - k0);    // wave-uniform
        int kq   = kmax & ~3;
        for (int k = 0; k < kq; k += 4) {
            int s = __shfl(mys, k + quad, 64);     // full wave
            uint4 raw = ((const uint4*)(xb + (size_t)s * DIN))[sub];
            const unsigned short* u = (const unsigned short*)&raw;
            #pragma unroll
            for (int j = 0; j < 8; ++j) acc[j] += bf2f(u[j]);
        }
        int rem = kmax - kq;           // wave-uniform, 0..3
        if (rem) {
            int srcl = kq + quad;
            if (srcl >= kmax) srcl = kmax - 1;
            int s = __shfl(mys, srcl, 64);         // full wave
            if (quad < rem) {
                uint4 raw = ((const uint4*)(xb + (size_t)s * DIN))[sub];
                const unsigned short* u = (const unsigned short*)&raw;
                #pragma unroll
                for (int j = 0; j < 8; ++j) acc[j] += bf2f(u[j]);
            }
        }
    }
    #pragma unroll
    for (int j = 0; j < 8; ++j) {
        acc[j] += __shfl_xor(acc[j], 32, 64);
        acc[j] += __shfl_xor(acc[j], 16, 64);
    }
    if (quad == 0) {
        float inv = 1.0f / fmaxf((float)d, 1.0f);
        unsigned short t[8];
        #pragma unroll
        for (int j = 0; j < 8; ++j) t[j] = f2bf(acc[j] * inv);
        *(uint4*)(aggb + (size_t)wave * DIN + sub * 8) = *(uint4*)t;
    }
}

// ---------------------------------------------------------------------------
// Gather-mean over bf16 P rows (64 cols = 128 B), accumulating into out.
// 8 lanes x 16 B per neighbor -> 8 neighbors concurrent.
// ---------------------------------------------------------------------------
__global__ __launch_bounds__(256) void agg_gather64_add(
    const int* __restrict__ row_start, const int* __restrict__ deg,
    const int* __restrict__ sorted_src, const unsigned short* __restrict__ P,
    float* __restrict__ out, int n)
{
    int wave = (blockIdx.x * 256 + threadIdx.x) >> 6;
    int lane = threadIdx.x & 63;
    if (wave >= n) return;
    int sub = lane & 7;
    int oct = lane >> 3;
    int base = row_start[wave];
    int d    = deg[wave];
    float acc[8];
    #pragma unroll
    for (int j = 0; j < 8; ++j) acc[j] = 0.f;

    for (int k0 = 0; k0 < d; k0 += 64) {
        int idx = k0 + lane;
        int mys = (idx < d) ? sorted_src[base + idx] : 0;
        int kmax = min(64, d - k0);
        int ko   = kmax & ~7;
        for (int k = 0; k < ko; k += 8) {
            int s = __shfl(mys, k + oct, 64);
            uint4 raw = ((const uint4*)(P + (size_t)s * DOUTC))[sub];
            const unsigned short* u = (const unsigned short*)&raw;
            #pragma unroll
            for (int j = 0; j < 8; ++j) acc[j] += bf2f(u[j]);
        }
        int rem = kmax - ko;
        if (rem) {
            int srcl = ko + oct;
            if (srcl >= kmax) srcl = kmax - 1;
            int s = __shfl(mys, srcl, 64);
            if (oct < rem) {
                uint4 raw = ((const uint4*)(P + (size_t)s * DOUTC))[sub];
                const unsigned short* u = (const unsigned short*)&raw;
                #pragma unroll
                for (int j = 0; j < 8; ++j) acc[j] += bf2f(u[j]);
            }
        }
    }
    #pragma unroll
    for (int j = 0; j < 8; ++j) {
        acc[j] += __shfl_xor(acc[j], 32, 64);
        acc[j] += __shfl_xor(acc[j], 16, 64);
        acc[j] += __shfl_xor(acc[j],  8, 64);
    }
    if (oct == 0) {
        float inv = 1.0f / fmaxf((float)d, 1.0f);
        float* op = out + (size_t)wave * DOUTC + sub * 8;
        float4 c0 = *(float4*)op;
        float4 c1 = *((float4*)op + 1);
        c0.x += acc[0] * inv; c0.y += acc[1] * inv;
        c0.z += acc[2] * inv; c0.w += acc[3] * inv;
        c1.x += acc[4] * inv; c1.y += acc[5] * inv;
        c1.z += acc[6] * inv; c1.w += acc[7] * inv;
        *(float4*)op = c0;
        *((float4*)op + 1) = c1;
    }
}

// ---------------------------------------------------------------------------
// GEMM1 (MFMA bf16): h = agg@Wl1 + x@Wr1 + b1, + fused BN partials.
// Block = 64 rows x 128 cols, 4 waves; wave w -> rows 16w..16w+15, all cols.
// K=256 as two phases (aggb vs W1p[0:128], xb vs W1p[128:256]) reusing one
// padded LDS A-tile [64][136] bf16 (frag ds_read_b128 conflict-free).
// B frags come straight from the pre-packed weight buffer (coalesced 1KB).
// A frag: lane holds A[m=lane&15][k=ks*32+(lane>>4)*8+j].
// C/D:    lane&15 = col, (lane>>4)*4+reg = row   [guide §3, m89-verified].
// ---------------------------------------------------------------------------
__global__ __launch_bounds__(256) void gemm1_mfma(
    const unsigned short* __restrict__ aggb, const unsigned short* __restrict__ xb,
    const unsigned short* __restrict__ W1p, const float* __restrict__ bias,
    float* __restrict__ h,
    float* __restrict__ bn_sum, float* __restrict__ bn_sumsq, int n)
{
    __shared__ union {
        unsigned short A[64][136];
        float red[2][4][128];
    } sm;

    const int block_row = blockIdx.x * 64;
    const int tid  = threadIdx.x;
    const int wave = tid >> 6;
    const int lane = tid & 63;
    const int q    = lane >> 4;
    const int m16  = lane & 15;

    f32x4 acc[8];
    #pragma unroll
    for (int nt = 0; nt < 8; ++nt) acc[nt] = (f32x4){0.f, 0.f, 0.f, 0.f};

    #pragma unroll
    for (int phase = 0; phase < 2; ++phase) {
        const unsigned short* src = phase ? xb : aggb;
        // stage 64x128 bf16 rows (16 uint4 chunks/row)
        #pragma unroll
        for (int i = 0; i < 4; ++i) {
            int idx = tid + i * 256;
            int r   = idx >> 4;
            int c16 = idx & 15;
            int g   = block_row + r;
            uint4 v = {0u, 0u, 0u, 0u};
            if (g < n) v = ((const uint4*)(src + (size_t)g * DIN))[c16];
            *(uint4*)&sm.A[r][c16 * 8] = v;
        }
        __syncthreads();

        #pragma unroll
        for (int ks = 0; ks < 4; ++ks) {
            bf16x8 a = *(const bf16x8*)&sm.A[wave * 16 + m16][ks * 32 + q * 8];
            const unsigned short* wp = W1p + (size_t)(phase * 4 + ks) * 8 * 512;
            #pragma unroll
            for (int nt = 0; nt < 8; ++nt) {
                bf16x8 b = *(const bf16x8*)(wp + nt * 512 + lane * 8);
                acc[nt] = __builtin_amdgcn_mfma_f32_16x16x32_bf16(a, b, acc[nt], 0, 0, 0);
            }
        }
        __syncthreads();
    }

    // epilogue: bias, store h, BN partials
    float psum[8], psq[8];
    #pragma unroll
    for (int nt = 0; nt < 8; ++nt) {
        int col = nt * 16 + m16;
        float bv = bias[col];
        float s = 0.f, ssq = 0.f;
        #pragma unroll
        for (int reg = 0; reg < 4; ++reg) {
            int g = block_row + wave * 16 + q * 4 + reg;
            float v = acc[nt][reg] + bv;
            if (g < n) {
                h[(size_t)g * DH + col] = v;
                s += v; ssq += v * v;
            }
        }
        psum[nt] = s; psq[nt] = ssq;
    }
    #pragma unroll
    for (int nt = 0; nt < 8; ++nt) {
        psum[nt] += __shfl_xor(psum[nt], 16, 64);
        psum[nt] += __shfl_xor(psum[nt], 32, 64);
        psq[nt]  += __shfl_xor(psq[nt], 16, 64);
        psq[nt]  += __shfl_xor(psq[nt], 32, 64);
    }
    if (lane < 16) {
        #pragma unroll
        for (int nt = 0; nt < 8; ++nt) {
            sm.red[0][wave][nt * 16 + lane] = psum[nt];
            sm.red[1][wave][nt * 16 + lane] = psq[nt];
        }
    }
    __syncthreads();
    if (tid < 128) {
        float s = sm.red[0][0][tid] + sm.red[0][1][tid] +
                  sm.red[0][2][tid] + sm.red[0][3][tid];
        float ssq = sm.red[1][0][tid] + sm.red[1][1][tid] +
                    sm.red[1][2][tid] + sm.red[1][3][tid];
        atomicAdd(&bn_sum[tid], s);
        atomicAdd(&bn_sumsq[tid], ssq);
    }
}

// ---------------------------------------------------------------------------
// BN finalize: scale = gamma*rsqrt(var+eps), shift = beta - mu*scale.
// ---------------------------------------------------------------------------
__global__ void bn_finalize_kernel(
    const float* __restrict__ bn_sum, const float* __restrict__ bn_sumsq,
    const float* __restrict__ gamma, const float* __restrict__ beta,
    float* __restrict__ scale, float* __restrict__ shift, int n_nodes)
{
    int c = threadIdx.x;
    if (c >= DH) return;
    float invN = 1.0f / (float)n_nodes;
    float mu  = bn_sum[c] * invN;
    float var = bn_sumsq[c] * invN - mu * mu;
    float sc  = gamma[c] * rsqrtf(var + BN_EPS);
    scale[c] = sc;
    shift[c] = beta[c] - mu * sc;
}

// ---------------------------------------------------------------------------
// GEMM2 (MFMA bf16) with fused BN+ReLU on load:
// a = relu(h*scale+shift) (bf16); cols 0..63 -> P = a@Wl2 (bf16 store),
// cols 64..127 -> out = a@Wr2 + b2 (fp32 store). K=128, pre-packed W2p.
// ---------------------------------------------------------------------------
__global__ __launch_bounds__(256) void gemm2p_mfma(
    const float* __restrict__ h,
    const float* __restrict__ scale, const float* __restrict__ shift,
    const unsigned short* __restrict__ W2p, const float* __restrict__ bias,
    unsigned short* __restrict__ P, float* __restrict__ out, int n)
{
    __shared__ unsigned short A[64][136];

    const int block_row = blockIdx.x * 64;
    const int tid  = threadIdx.x;
    const int wave = tid >> 6;
    const int lane = tid & 63;
    const int q    = lane >> 4;
    const int m16  = lane & 15;

    // stage relu(h*scale+shift) as bf16: 64 rows x 32 float4-chunks
    #pragma unroll
    for (int i = 0; i < 8; ++i) {
        int idx = tid + i * 256;
        int r   = idx >> 5;
        int c4  = idx & 31;
        int g   = block_row + r;
        unsigned short t[4] = {0, 0, 0, 0};
        if (g < n) {
            float4 raw = ((const float4*)(h + (size_t)g * DH))[c4];
            float4 sc = ((const float4*)scale)[c4];
            float4 sh = ((const float4*)shift)[c4];
            t[0] = f2bf(fmaxf(raw.x * sc.x + sh.x, 0.f));
            t[1] = f2bf(fmaxf(raw.y * sc.y + sh.y, 0.f));
            t[2] = f2bf(fmaxf(raw.z * sc.z + sh.z, 0.f));
            t[3] = f2bf(fmaxf(raw.w * sc.w + sh.w, 0.f));
        }
        *(uint2*)&A[r][c4 * 4] = *(uint2*)t;
    }
    __syncthreads();

    f32x4 acc[8];
    #pragma unroll
    for (int nt = 0; nt < 8; ++nt) acc[nt] = (f32x4){0.f, 0.f, 0.f, 0.f};

    #pragma unroll
    for (int ks = 0; ks < 4; ++ks) {
        bf16x8 a = *(const bf16x8*)&A[wave * 16 + m16][ks * 32 + q * 8];
        const unsigned short* wp = W2p + (size_t)ks * 8 * 512;
        #pragma unroll
        for (int nt = 0; nt < 8; ++nt) {
            bf16x8 b = *(const bf16x8*)(wp + nt * 512 + lane * 8);
            acc[nt] = __builtin_amdgcn_mfma_f32_16x16x32_bf16(a, b, acc[nt], 0, 0, 0);
        }
    }

    // epilogue: nt 0..3 -> P (bf16), nt 4..7 -> out (+bias, fp32)
    #pragma unroll
    for (int nt = 0; nt < 4; ++nt) {
        int col = nt * 16 + m16;
        #pragma unroll
        for (int reg = 0; reg < 4; ++reg) {
            int g = block_row + wave * 16 + q * 4 + reg;
            if (g < n) P[(size_t)g * DOUTC + col] = f2bf(acc[nt][reg]);
        }
    }
    #pragma unroll
    for (int nt = 4; nt < 8; ++nt) {
        int col = (nt - 4) * 16 + m16;
        float bv = bias[col];
        #pragma unroll
        for (int reg = 0; reg < 4; ++reg) {
            int g = block_row + wave * 16 + q * 4 + reg;
            if (g < n) out[(size_t)g * DOUTC + col] = acc[nt][reg] + bv;
        }
    }
}

// ---------------------------------------------------------------------------
extern "C" void kernel_launch(void* const* d_in, const int* in_sizes, int n_in,
                              void* d_out, int out_size, void* d_ws, size_t ws_size,
                              hipStream_t stream)
{
    const float* x     = (const float*)d_in[0];
    const int*   ei    = (const int*)  d_in[1];
    const float* Wl1   = (const float*)d_in[2];
    const float* Wr1   = (const float*)d_in[3];
    const float* b1    = (const float*)d_in[4];
    const float* gamma = (const float*)d_in[5];
    const float* beta  = (const float*)d_in[6];
    const float* Wl2   = (const float*)d_in[7];
    const float* Wr2   = (const float*)d_in[8];
    const float* b2    = (const float*)d_in[9];
    float*       out   = (float*)d_out;

    const int N = in_sizes[0] / DIN;      // 50000
    const int E = in_sizes[1] / 2;        // 800000

    // workspace layout (16B alignment maintained across segments)
    float* ws       = (float*)d_ws;
    float* h        = ws;                            // N*128 f32
    float* bn_sum   = h + (size_t)N * DH;            // 128
    float* bn_sumsq = bn_sum + DH;                   // 128
    float* scale    = bn_sumsq + DH;                 // 128
    float* shift    = scale + DH;                    // 128
    int* deg        = (int*)(shift + DH);            // N
    int* fill       = deg + N;                       // N
    int* cursor     = fill + N;                      // 4 (padded for align)
    int* row_start  = cursor + 4;                    // N
    int* sorted_src = row_start + N;                 // E
    unsigned short* aggb = (unsigned short*)(sorted_src + E);  // N*128 bf16
    unsigned short* xb   = aggb + (size_t)N * DIN;   // N*128 bf16
    unsigned short* P    = xb + (size_t)N * DIN;     // N*64 bf16
    unsigned short* W1p  = P + (size_t)N * DOUTC;    // 256*128 bf16
    unsigned short* W2p  = W1p + 256 * 128;          // 128*128 bf16

    // zero: bn_sum, bn_sumsq, scale, shift, deg, fill, cursor[4]
    hipMemsetAsync(bn_sum, 0, (4 * DH + 2 * (size_t)N + 4) * sizeof(float), stream);

    dim3 blk(256);
    const int edge_blocks = (E + 255) / 256;
    const int node_blocks = (N + 255) / 256;
    const int wave_blocks = (N + 3) / 4;
    const int gemm_blocks = (N + 63) / 64;
    const int cvt_blocks  = ((size_t)N * DIN / 8 + 255) / 256;

    // ---- conversions & weight packing ----
    cvt_bf16_kernel<<<cvt_blocks, blk, 0, stream>>>(x, xb, N * DIN / 8);
    pack_w_kernel<<<64, blk, 0, stream>>>(Wl1, W1p, 128);
    pack_w_kernel<<<64, blk, 0, stream>>>(Wr1, W1p + 128 * 128, 128);
    pack_wcat_kernel<<<64, blk, 0, stream>>>(Wl2, Wr2, W2p, 128);

    // ---- CSR build (by dst) ----
    hist_kernel<<<edge_blocks, blk, 0, stream>>>(ei, deg, E);
    alloc_kernel<<<node_blocks, blk, 0, stream>>>(deg, row_start, cursor, N);
    bucket_kernel<<<edge_blocks, blk, 0, stream>>>(ei, row_start, fill, sorted_src, E);

    // ---- layer 1 ----
    agg_gather128<<<wave_blocks, blk, 0, stream>>>(row_start, deg, sorted_src,
                                                   xb, aggb, N);
    gemm1_mfma<<<gemm_blocks, blk, 0, stream>>>(aggb, xb, W1p, b1, h,
                                                bn_sum, bn_sumsq, N);
    bn_finalize_kernel<<<1, 128, 0, stream>>>(bn_sum, bn_sumsq, gamma, beta,
                                              scale, shift, N);

    // ---- layer 2 (BN+ReLU fused; project-then-gather) ----
    gemm2p_mfma<<<gemm_blocks, blk, 0, stream>>>(h, scale, shift, W2p, b2,
                                                 P, out, N);
    agg_gather64_add<<<wave_blocks, blk, 0, stream>>>(row_start, deg, sorted_src,
                                                      P, out, N);
}

// Round 7
// 228.005 us; speedup vs baseline: 13.0687x; 1.3345x over previous
//
#include <hip/hip_runtime.h>
#include <hip/hip_bf16.h>

#define DIN   128
#define DH    128
#define DOUTC 64
#define BN_EPS 1e-5f

typedef __attribute__((ext_vector_type(8))) short bf16x8;
typedef __attribute__((ext_vector_type(4))) float f32x4;

__device__ inline unsigned short f2bf(float f) {
    __hip_bfloat16 b = __float2bfloat16(f);
    return *reinterpret_cast<unsigned short*>(&b);
}
__device__ inline float bf2f(unsigned short u) {
    return __uint_as_float(((unsigned int)u) << 16);
}

// ---------------------------------------------------------------------------
// Exclusive prefix scan over 256 LDS ints (all 256 threads must call).
// ---------------------------------------------------------------------------
__device__ inline void block_excl_scan_256(const int* __restrict__ arr,
                                           int* __restrict__ excl,
                                           int* __restrict__ wsum, int tid)
{
    int lane = tid & 63, w = tid >> 6;
    int v = arr[tid];
    int inc = v;
    #pragma unroll
    for (int off = 1; off < 64; off <<= 1) {
        int t = __shfl_up(inc, off, 64);
        if (lane >= off) inc += t;
    }
    if (lane == 63) wsum[w] = inc;
    __syncthreads();
    if (tid == 0) {
        int s = 0;
        #pragma unroll
        for (int i = 0; i < 4; ++i) { int t = wsum[i]; wsum[i] = s; s += t; }
    }
    __syncthreads();
    excl[tid] = inc - v + wsum[w];
    __syncthreads();
}

// ---------------------------------------------------------------------------
// fp32 -> bf16 convert (8 elements / thread).
// ---------------------------------------------------------------------------
__global__ __launch_bounds__(256) void cvt_bf16_kernel(
    const float* __restrict__ src, unsigned short* __restrict__ dst, int total8)
{
    int i = blockIdx.x * 256 + threadIdx.x;
    if (i >= total8) return;
    float4 a = ((const float4*)src)[2 * i];
    float4 b = ((const float4*)src)[2 * i + 1];
    unsigned short t[8];
    t[0]=f2bf(a.x); t[1]=f2bf(a.y); t[2]=f2bf(a.z); t[3]=f2bf(a.w);
    t[4]=f2bf(b.x); t[5]=f2bf(b.y); t[6]=f2bf(b.z); t[7]=f2bf(b.w);
    *(uint4*)(dst + (size_t)i * 8) = *(uint4*)t;
}

// ---------------------------------------------------------------------------
// Pack weights into MFMA B-fragment order (bf16), all three in one launch.
// dst[(k/32*8 + c/16)*512 + ((k/8)&3)*128 + (c&15)*8 + (k&7)] = W[k][c]
// region 0: Wl1 -> W1p[0:]; region 1: Wr1 -> W1p[16384:]; region 2: [Wl2|Wr2] -> W2p.
// ---------------------------------------------------------------------------
__global__ __launch_bounds__(256) void pack_all_kernel(
    const float* __restrict__ Wl1, const float* __restrict__ Wr1,
    const float* __restrict__ Wl2, const float* __restrict__ Wr2,
    unsigned short* __restrict__ W1p, unsigned short* __restrict__ W2p)
{
    int region = blockIdx.x >> 6;
    int idx = (blockIdx.x & 63) * 256 + threadIdx.x;   // 0..16383
    int k = idx >> 7, c = idx & 127;
    int d = ((k >> 5) * 8 + (c >> 4)) * 512 + ((k >> 3) & 3) * 128 + (c & 15) * 8 + (k & 7);
    if (region == 0) {
        W1p[d] = f2bf(Wl1[idx]);
    } else if (region == 1) {
        W1p[128 * 128 + d] = f2bf(Wr1[idx]);
    } else {
        float v = (c < 64) ? Wl2[k * 64 + c] : Wr2[k * 64 + (c - 64)];
        W2p[d] = f2bf(v);
    }
}

// ---------------------------------------------------------------------------
// Counting sort pass A: bin edges into coarse buckets (dst>>8) with
// block-contiguous run writes (LDS reorder + one atomic per bucket/block).
// rec = (dst<<16)|src (both < 65536). Writes mostly full-line sequential.
// ---------------------------------------------------------------------------
__global__ __launch_bounds__(256) void bin_coarse(
    const int* __restrict__ ei, int* __restrict__ cursor,
    unsigned int* __restrict__ coarse, int E, int nb, int cap)
{
    __shared__ int hist[256], lstart[256], gbase[256], wsum[4];
    __shared__ unsigned int staged[4096];
    const int tid = threadIdx.x;
    const int chunkBase = blockIdx.x * 4096;

    hist[tid] = 0;
    __syncthreads();

    unsigned int rec[16]; int pos[16]; int bb[16];
    #pragma unroll
    for (int i = 0; i < 16; ++i) {
        int e = chunkBase + i * 256 + tid;
        if (e < E) {
            int s = ei[e], d = ei[E + e];
            rec[i] = ((unsigned int)d << 16) | (unsigned int)s;
            bb[i]  = d >> 8;
            pos[i] = atomicAdd(&hist[bb[i]], 1);
        } else bb[i] = -1;
    }
    __syncthreads();

    block_excl_scan_256(hist, lstart, wsum, tid);

    if (tid < nb) {
        int c = hist[tid];
        gbase[tid] = c ? atomicAdd(&cursor[tid], c) : 0;
    }
    __syncthreads();

    #pragma unroll
    for (int i = 0; i < 16; ++i)
        if (bb[i] >= 0) staged[lstart[bb[i]] + pos[i]] = rec[i];
    __syncthreads();

    int total = min(4096, E - chunkBase);
    for (int i = tid; i < total; i += 256) {
        unsigned int r = staged[i];
        int b   = (int)(r >> 24);          // dst>>8
        int gp  = gbase[b] + (i - lstart[b]);
        if (gp < cap) coarse[(size_t)b * cap + gp] = r;
    }
}

// ---------------------------------------------------------------------------
// Counting sort pass B: one block per coarse bucket. LDS histogram over the
// bucket's 256 nodes -> prefix -> scatter src (ushort) into the bucket's own
// window (single-CU locality). Emits deg / row_start.
// ---------------------------------------------------------------------------
__global__ __launch_bounds__(256) void bin_fine(
    const int* __restrict__ cursor, const unsigned int* __restrict__ coarse,
    unsigned short* __restrict__ sorted, int* __restrict__ deg,
    int* __restrict__ row_start, int n, int cap)
{
    __shared__ int hist[256], pstart[256], cur2[256], wsum[4];
    const int b = blockIdx.x, tid = threadIdx.x;
    const int cnt = min(cursor[b], cap);
    const unsigned int* src = coarse + (size_t)b * cap;

    hist[tid] = 0;
    __syncthreads();

    int nIter = (cnt + 255) >> 8;
    for (int i = 0; i < nIter; ++i) {
        int idx = i * 256 + tid;
        if (idx < cnt) atomicAdd(&hist[(src[idx] >> 16) & 255], 1);
    }
    __syncthreads();

    block_excl_scan_256(hist, pstart, wsum, tid);
    cur2[tid] = pstart[tid];
    __syncthreads();

    for (int i = 0; i < nIter; ++i) {
        int idx = i * 256 + tid;
        if (idx < cnt) {
            unsigned int r = src[idx];           // L1/L2 re-read
            int dl = (r >> 16) & 255;
            int p  = atomicAdd(&cur2[dl], 1);
            sorted[(size_t)b * cap + p] = (unsigned short)(r & 0xFFFFu);
        }
    }

    int node = b * 256 + tid;
    if (node < n) {
        deg[node]       = hist[tid];
        row_start[node] = b * cap + pstart[tid];
    }
}

// ---------------------------------------------------------------------------
// Gather-mean over bf16 x rows (128 cols = 256 B). One wave per node;
// 16 lanes x 16 B per neighbor -> 4 neighbors concurrent. All __shfl full-wave.
// ---------------------------------------------------------------------------
__global__ __launch_bounds__(256) void agg_gather128(
    const int* __restrict__ row_start, const int* __restrict__ deg,
    const unsigned short* __restrict__ sorted, const unsigned short* __restrict__ xb,
    unsigned short* __restrict__ aggb, int n)
{
    int wave = (blockIdx.x * 256 + threadIdx.x) >> 6;
    int lane = threadIdx.x & 63;
    if (wave >= n) return;
    int sub  = lane & 15;
    int quad = lane >> 4;
    int base = row_start[wave];
    int d    = deg[wave];
    float acc[8];
    #pragma unroll
    for (int j = 0; j < 8; ++j) acc[j] = 0.f;

    for (int k0 = 0; k0 < d; k0 += 64) {
        int idx = k0 + lane;
        int mys = (idx < d) ? (int)sorted[base + idx] : 0;
        int kmax = min(64, d - k0);    // wave-uniform
        int kq   = kmax & ~3;
        for (int k = 0; k < kq; k += 4) {
            int s = __shfl(mys, k + quad, 64);
            uint4 raw = ((const uint4*)(xb + (size_t)s * DIN))[sub];
            const unsigned short* u = (const unsigned short*)&raw;
            #pragma unroll
            for (int j = 0; j < 8; ++j) acc[j] += bf2f(u[j]);
        }
        int rem = kmax - kq;
        if (rem) {
            int srcl = kq + quad;
            if (srcl >= kmax) srcl = kmax - 1;
            int s = __shfl(mys, srcl, 64);         // full wave
            if (quad < rem) {
                uint4 raw = ((const uint4*)(xb + (size_t)s * DIN))[sub];
                const unsigned short* u = (const unsigned short*)&raw;
                #pragma unroll
                for (int j = 0; j < 8; ++j) acc[j] += bf2f(u[j]);
            }
        }
    }
    #pragma unroll
    for (int j = 0; j < 8; ++j) {
        acc[j] += __shfl_xor(acc[j], 32, 64);
        acc[j] += __shfl_xor(acc[j], 16, 64);
    }
    if (quad == 0) {
        float inv = 1.0f / fmaxf((float)d, 1.0f);
        unsigned short t[8];
        #pragma unroll
        for (int j = 0; j < 8; ++j) t[j] = f2bf(acc[j] * inv);
        *(uint4*)(aggb + (size_t)wave * DIN + sub * 8) = *(uint4*)t;
    }
}

// ---------------------------------------------------------------------------
// Gather-mean over bf16 P rows (64 cols = 128 B), accumulating into out.
// 8 lanes x 16 B per neighbor -> 8 neighbors concurrent.
// ---------------------------------------------------------------------------
__global__ __launch_bounds__(256) void agg_gather64_add(
    const int* __restrict__ row_start, const int* __restrict__ deg,
    const unsigned short* __restrict__ sorted, const unsigned short* __restrict__ P,
    float* __restrict__ out, int n)
{
    int wave = (blockIdx.x * 256 + threadIdx.x) >> 6;
    int lane = threadIdx.x & 63;
    if (wave >= n) return;
    int sub = lane & 7;
    int oct = lane >> 3;
    int base = row_start[wave];
    int d    = deg[wave];
    float acc[8];
    #pragma unroll
    for (int j = 0; j < 8; ++j) acc[j] = 0.f;

    for (int k0 = 0; k0 < d; k0 += 64) {
        int idx = k0 + lane;
        int mys = (idx < d) ? (int)sorted[base + idx] : 0;
        int kmax = min(64, d - k0);
        int ko   = kmax & ~7;
        for (int k = 0; k < ko; k += 8) {
            int s = __shfl(mys, k + oct, 64);
            uint4 raw = ((const uint4*)(P + (size_t)s * DOUTC))[sub];
            const unsigned short* u = (const unsigned short*)&raw;
            #pragma unroll
            for (int j = 0; j < 8; ++j) acc[j] += bf2f(u[j]);
        }
        int rem = kmax - ko;
        if (rem) {
            int srcl = ko + oct;
            if (srcl >= kmax) srcl = kmax - 1;
            int s = __shfl(mys, srcl, 64);
            if (oct < rem) {
                uint4 raw = ((const uint4*)(P + (size_t)s * DOUTC))[sub];
                const unsigned short* u = (const unsigned short*)&raw;
                #pragma unroll
                for (int j = 0; j < 8; ++j) acc[j] += bf2f(u[j]);
            }
        }
    }
    #pragma unroll
    for (int j = 0; j < 8; ++j) {
        acc[j] += __shfl_xor(acc[j], 32, 64);
        acc[j] += __shfl_xor(acc[j], 16, 64);
        acc[j] += __shfl_xor(acc[j],  8, 64);
    }
    if (oct == 0) {
        float inv = 1.0f / fmaxf((float)d, 1.0f);
        float* op = out + (size_t)wave * DOUTC + sub * 8;
        float4 c0 = *(float4*)op;
        float4 c1 = *((float4*)op + 1);
        c0.x += acc[0] * inv; c0.y += acc[1] * inv;
        c0.z += acc[2] * inv; c0.w += acc[3] * inv;
        c1.x += acc[4] * inv; c1.y += acc[5] * inv;
        c1.z += acc[6] * inv; c1.w += acc[7] * inv;
        *(float4*)op = c0;
        *((float4*)op + 1) = c1;
    }
}

// ---------------------------------------------------------------------------
// GEMM1 (MFMA bf16): h = agg@Wl1 + x@Wr1 + b1, + fused BN partials.
// ---------------------------------------------------------------------------
__global__ __launch_bounds__(256) void gemm1_mfma(
    const unsigned short* __restrict__ aggb, const unsigned short* __restrict__ xb,
    const unsigned short* __restrict__ W1p, const float* __restrict__ bias,
    float* __restrict__ h,
    float* __restrict__ bn_sum, float* __restrict__ bn_sumsq, int n)
{
    __shared__ union {
        unsigned short A[64][136];
        float red[2][4][128];
    } sm;

    const int block_row = blockIdx.x * 64;
    const int tid  = threadIdx.x;
    const int wave = tid >> 6;
    const int lane = tid & 63;
    const int q    = lane >> 4;
    const int m16  = lane & 15;

    f32x4 acc[8];
    #pragma unroll
    for (int nt = 0; nt < 8; ++nt) acc[nt] = (f32x4){0.f, 0.f, 0.f, 0.f};

    #pragma unroll
    for (int phase = 0; phase < 2; ++phase) {
        const unsigned short* src = phase ? xb : aggb;
        #pragma unroll
        for (int i = 0; i < 4; ++i) {
            int idx = tid + i * 256;
            int r   = idx >> 4;
            int c16 = idx & 15;
            int g   = block_row + r;
            uint4 v = {0u, 0u, 0u, 0u};
            if (g < n) v = ((const uint4*)(src + (size_t)g * DIN))[c16];
            *(uint4*)&sm.A[r][c16 * 8] = v;
        }
        __syncthreads();

        #pragma unroll
        for (int ks = 0; ks < 4; ++ks) {
            bf16x8 a = *(const bf16x8*)&sm.A[wave * 16 + m16][ks * 32 + q * 8];
            const unsigned short* wp = W1p + (size_t)(phase * 4 + ks) * 8 * 512;
            #pragma unroll
            for (int nt = 0; nt < 8; ++nt) {
                bf16x8 b = *(const bf16x8*)(wp + nt * 512 + lane * 8);
                acc[nt] = __builtin_amdgcn_mfma_f32_16x16x32_bf16(a, b, acc[nt], 0, 0, 0);
            }
        }
        __syncthreads();
    }

    float psum[8], psq[8];
    #pragma unroll
    for (int nt = 0; nt < 8; ++nt) {
        int col = nt * 16 + m16;
        float bv = bias[col];
        float s = 0.f, ssq = 0.f;
        #pragma unroll
        for (int reg = 0; reg < 4; ++reg) {
            int g = block_row + wave * 16 + q * 4 + reg;
            float v = acc[nt][reg] + bv;
            if (g < n) {
                h[(size_t)g * DH + col] = v;
                s += v; ssq += v * v;
            }
        }
        psum[nt] = s; psq[nt] = ssq;
    }
    #pragma unroll
    for (int nt = 0; nt < 8; ++nt) {
        psum[nt] += __shfl_xor(psum[nt], 16, 64);
        psum[nt] += __shfl_xor(psum[nt], 32, 64);
        psq[nt]  += __shfl_xor(psq[nt], 16, 64);
        psq[nt]  += __shfl_xor(psq[nt], 32, 64);
    }
    if (lane < 16) {
        #pragma unroll
        for (int nt = 0; nt < 8; ++nt) {
            sm.red[0][wave][nt * 16 + lane] = psum[nt];
            sm.red[1][wave][nt * 16 + lane] = psq[nt];
        }
    }
    __syncthreads();
    if (tid < 128) {
        float s = sm.red[0][0][tid] + sm.red[0][1][tid] +
                  sm.red[0][2][tid] + sm.red[0][3][tid];
        float ssq = sm.red[1][0][tid] + sm.red[1][1][tid] +
                    sm.red[1][2][tid] + sm.red[1][3][tid];
        atomicAdd(&bn_sum[tid], s);
        atomicAdd(&bn_sumsq[tid], ssq);
    }
}

// ---------------------------------------------------------------------------
__global__ void bn_finalize_kernel(
    const float* __restrict__ bn_sum, const float* __restrict__ bn_sumsq,
    const float* __restrict__ gamma, const float* __restrict__ beta,
    float* __restrict__ scale, float* __restrict__ shift, int n_nodes)
{
    int c = threadIdx.x;
    if (c >= DH) return;
    float invN = 1.0f / (float)n_nodes;
    float mu  = bn_sum[c] * invN;
    float var = bn_sumsq[c] * invN - mu * mu;
    float sc  = gamma[c] * rsqrtf(var + BN_EPS);
    scale[c] = sc;
    shift[c] = beta[c] - mu * sc;
}

// ---------------------------------------------------------------------------
// GEMM2 (MFMA bf16) with fused BN+ReLU on load.
// ---------------------------------------------------------------------------
__global__ __launch_bounds__(256) void gemm2p_mfma(
    const float* __restrict__ h,
    const float* __restrict__ scale, const float* __restrict__ shift,
    const unsigned short* __restrict__ W2p, const float* __restrict__ bias,
    unsigned short* __restrict__ P, float* __restrict__ out, int n)
{
    __shared__ unsigned short A[64][136];

    const int block_row = blockIdx.x * 64;
    const int tid  = threadIdx.x;
    const int wave = tid >> 6;
    const int lane = tid & 63;
    const int q    = lane >> 4;
    const int m16  = lane & 15;

    #pragma unroll
    for (int i = 0; i < 8; ++i) {
        int idx = tid + i * 256;
        int r   = idx >> 5;
        int c4  = idx & 31;
        int g   = block_row + r;
        unsigned short t[4] = {0, 0, 0, 0};
        if (g < n) {
            float4 raw = ((const float4*)(h + (size_t)g * DH))[c4];
            float4 sc = ((const float4*)scale)[c4];
            float4 sh = ((const float4*)shift)[c4];
            t[0] = f2bf(fmaxf(raw.x * sc.x + sh.x, 0.f));
            t[1] = f2bf(fmaxf(raw.y * sc.y + sh.y, 0.f));
            t[2] = f2bf(fmaxf(raw.z * sc.z + sh.z, 0.f));
            t[3] = f2bf(fmaxf(raw.w * sc.w + sh.w, 0.f));
        }
        *(uint2*)&A[r][c4 * 4] = *(uint2*)t;
    }
    __syncthreads();

    f32x4 acc[8];
    #pragma unroll
    for (int nt = 0; nt < 8; ++nt) acc[nt] = (f32x4){0.f, 0.f, 0.f, 0.f};

    #pragma unroll
    for (int ks = 0; ks < 4; ++ks) {
        bf16x8 a = *(const bf16x8*)&A[wave * 16 + m16][ks * 32 + q * 8];
        const unsigned short* wp = W2p + (size_t)ks * 8 * 512;
        #pragma unroll
        for (int nt = 0; nt < 8; ++nt) {
            bf16x8 b = *(const bf16x8*)(wp + nt * 512 + lane * 8);
            acc[nt] = __builtin_amdgcn_mfma_f32_16x16x32_bf16(a, b, acc[nt], 0, 0, 0);
        }
    }

    #pragma unroll
    for (int nt = 0; nt < 4; ++nt) {
        int col = nt * 16 + m16;
        #pragma unroll
        for (int reg = 0; reg < 4; ++reg) {
            int g = block_row + wave * 16 + q * 4 + reg;
            if (g < n) P[(size_t)g * DOUTC + col] = f2bf(acc[nt][reg]);
        }
    }
    #pragma unroll
    for (int nt = 4; nt < 8; ++nt) {
        int col = (nt - 4) * 16 + m16;
        float bv = bias[col];
        #pragma unroll
        for (int reg = 0; reg < 4; ++reg) {
            int g = block_row + wave * 16 + q * 4 + reg;
            if (g < n) out[(size_t)g * DOUTC + col] = acc[nt][reg] + bv;
        }
    }
}

// ---------------------------------------------------------------------------
extern "C" void kernel_launch(void* const* d_in, const int* in_sizes, int n_in,
                              void* d_out, int out_size, void* d_ws, size_t ws_size,
                              hipStream_t stream)
{
    const float* x     = (const float*)d_in[0];
    const int*   ei    = (const int*)  d_in[1];
    const float* Wl1   = (const float*)d_in[2];
    const float* Wr1   = (const float*)d_in[3];
    const float* b1    = (const float*)d_in[4];
    const float* gamma = (const float*)d_in[5];
    const float* beta  = (const float*)d_in[6];
    const float* Wl2   = (const float*)d_in[7];
    const float* Wr2   = (const float*)d_in[8];
    const float* b2    = (const float*)d_in[9];
    float*       out   = (float*)d_out;

    const int N = in_sizes[0] / DIN;      // 50000
    const int E = in_sizes[1] / 2;        // 800000

    const int NB  = (N + 255) >> 8;                       // coarse buckets (196)
    int cap = (E / NB) * 3 / 2 + 256;                     // per-bucket capacity
    cap = (cap + 255) & ~255;                             // multiple of 256

    // workspace layout (all segment byte-sizes multiples of 16)
    float* h        = (float*)d_ws;                       // N*128 f32
    float* bn_sum   = h + (size_t)N * DH;                 // 128
    float* bn_sumsq = bn_sum + DH;                        // 128
    float* scale    = bn_sumsq + DH;                      // 128
    float* shift    = scale + DH;                         // 128
    int* cursor     = (int*)(shift + DH);                 // 256
    int* deg        = cursor + 256;                       // N
    int* row_start  = deg + N;                            // N
    unsigned int* coarse   = (unsigned int*)(row_start + N);      // NB*cap
    unsigned short* sorted = (unsigned short*)(coarse + (size_t)NB * cap); // NB*cap
    unsigned short* aggb   = sorted + (size_t)NB * cap;   // N*128 bf16
    unsigned short* xb     = aggb + (size_t)N * DIN;      // N*128 bf16
    unsigned short* P      = xb + (size_t)N * DIN;        // N*64 bf16
    unsigned short* W1p    = P + (size_t)N * DOUTC;       // 256*128 bf16
    unsigned short* W2p    = W1p + 256 * 128;             // 128*128 bf16

    // zero bn sums + scale/shift (harmless) + coarse cursors
    hipMemsetAsync(bn_sum, 0, (4 * DH + 256) * sizeof(float), stream);

    dim3 blk(256);
    const int binA_blocks = (E + 4095) / 4096;
    const int wave_blocks = (N + 3) / 4;
    const int gemm_blocks = (N + 63) / 64;
    const int cvt_blocks  = ((size_t)N * DIN / 8 + 255) / 256;

    // ---- conversions & weight packing ----
    cvt_bf16_kernel<<<cvt_blocks, blk, 0, stream>>>(x, xb, N * DIN / 8);
    pack_all_kernel<<<192, blk, 0, stream>>>(Wl1, Wr1, Wl2, Wr2, W1p, W2p);

    // ---- CSR build: two-pass LDS counting sort (block-contiguous writes) ----
    bin_coarse<<<binA_blocks, blk, 0, stream>>>(ei, cursor, coarse, E, NB, cap);
    bin_fine<<<NB, blk, 0, stream>>>(cursor, coarse, sorted, deg, row_start, N, cap);

    // ---- layer 1 ----
    agg_gather128<<<wave_blocks, blk, 0, stream>>>(row_start, deg, sorted,
                                                   xb, aggb, N);
    gemm1_mfma<<<gemm_blocks, blk, 0, stream>>>(aggb, xb, W1p, b1, h,
                                                bn_sum, bn_sumsq, N);
    bn_finalize_kernel<<<1, 128, 0, stream>>>(bn_sum, bn_sumsq, gamma, beta,
                                              scale, shift, N);

    // ---- layer 2 (BN+ReLU fused; project-then-gather) ----
    gemm2p_mfma<<<gemm_blocks, blk, 0, stream>>>(h, scale, shift, W2p, b2,
                                                 P, out, N);
    agg_gather64_add<<<wave_blocks, blk, 0, stream>>>(row_start, deg, sorted,
                                                      P, out, N);
}

// Round 8
// 221.332 us; speedup vs baseline: 13.4627x; 1.0301x over previous
//
#include <hip/hip_runtime.h>
#include <hip/hip_bf16.h>
#include <hip/hip_fp8.h>

#define DIN   128
#define DH    128
#define DOUTC 64
#define BN_EPS 1e-5f

typedef __attribute__((ext_vector_type(8))) short bf16x8;
typedef __attribute__((ext_vector_type(4))) float f32x4;
typedef __attribute__((ext_vector_type(2))) float f32x2;

#ifndef __has_builtin
#define __has_builtin(x) 0
#endif
#if __has_builtin(__builtin_amdgcn_cvt_pk_f32_fp8) && __has_builtin(__builtin_amdgcn_cvt_pk_fp8_f32)
#define HW_FP8 1
#else
#define HW_FP8 0
#endif

__device__ inline unsigned short f2bf(float f) {
    __hip_bfloat16 b = __float2bfloat16(f);
    return *reinterpret_cast<unsigned short*>(&b);
}
__device__ inline float bf2f(unsigned short u) {
    return __uint_as_float(((unsigned int)u) << 16);
}

// 4 fp8(e4m3fn) bytes in a dword -> 4 floats (order: byte0..byte3)
__device__ inline void fp8x4_to_f32(unsigned int w, float* o) {
#if HW_FP8
    f32x2 lo = __builtin_amdgcn_cvt_pk_f32_fp8((int)w, false);
    f32x2 hi = __builtin_amdgcn_cvt_pk_f32_fp8((int)w, true);
    o[0] = lo.x; o[1] = lo.y; o[2] = hi.x; o[3] = hi.y;
#else
    #pragma unroll
    for (int c = 0; c < 4; ++c) {
        __hip_fp8_e4m3 q; q.__x = (__hip_fp8_storage_t)((w >> (8 * c)) & 0xFF);
        o[c] = (float)q;
    }
#endif
}
__device__ inline unsigned int f32x4_to_fp8(float a, float b, float c, float d) {
#if HW_FP8
    int p = __builtin_amdgcn_cvt_pk_fp8_f32(a, b, 0, false);
    p = __builtin_amdgcn_cvt_pk_fp8_f32(c, d, p, true);
    return (unsigned int)p;
#else
    __hip_fp8_e4m3 qa(a), qb(b), qc(c), qd(d);
    return (unsigned int)qa.__x | ((unsigned int)qb.__x << 8) |
           ((unsigned int)qc.__x << 16) | ((unsigned int)qd.__x << 24);
#endif
}

// ---------------------------------------------------------------------------
// Exclusive prefix scan over 256 LDS ints (all 256 threads must call).
// ---------------------------------------------------------------------------
__device__ inline void block_excl_scan_256(const int* __restrict__ arr,
                                           int* __restrict__ excl,
                                           int* __restrict__ wsum, int tid)
{
    int lane = tid & 63, w = tid >> 6;
    int v = arr[tid];
    int inc = v;
    #pragma unroll
    for (int off = 1; off < 64; off <<= 1) {
        int t = __shfl_up(inc, off, 64);
        if (lane >= off) inc += t;
    }
    if (lane == 63) wsum[w] = inc;
    __syncthreads();
    if (tid == 0) {
        int s = 0;
        #pragma unroll
        for (int i = 0; i < 4; ++i) { int t = wsum[i]; wsum[i] = s; s += t; }
    }
    __syncthreads();
    excl[tid] = inc - v + wsum[w];
    __syncthreads();
}

// ---------------------------------------------------------------------------
// Fused conversions: region A (cvt_blocks): x -> xb (bf16) and xq (fp8 e4m3).
// Region B (192 blocks): pack Wl1/Wr1/[Wl2|Wr2] into MFMA B-frag order:
// dst[(k/32*8 + c/16)*512 + ((k/8)&3)*128 + (c&15)*8 + (k&7)] = W[k][c].
// ---------------------------------------------------------------------------
__global__ __launch_bounds__(256) void cvtpack_kernel(
    const float* __restrict__ x, unsigned short* __restrict__ xb,
    unsigned char* __restrict__ xq,
    const float* __restrict__ Wl1, const float* __restrict__ Wr1,
    const float* __restrict__ Wl2, const float* __restrict__ Wr2,
    unsigned short* __restrict__ W1p, unsigned short* __restrict__ W2p,
    int total8, int cvt_blocks)
{
    int b = blockIdx.x;
    if (b < cvt_blocks) {
        int i = b * 256 + threadIdx.x;
        if (i >= total8) return;
        float4 a = ((const float4*)x)[2 * i];
        float4 c = ((const float4*)x)[2 * i + 1];
        unsigned short t[8];
        t[0]=f2bf(a.x); t[1]=f2bf(a.y); t[2]=f2bf(a.z); t[3]=f2bf(a.w);
        t[4]=f2bf(c.x); t[5]=f2bf(c.y); t[6]=f2bf(c.z); t[7]=f2bf(c.w);
        *(uint4*)(xb + (size_t)i * 8) = *(uint4*)t;
        uint2 pk;
        pk.x = f32x4_to_fp8(a.x, a.y, a.z, a.w);
        pk.y = f32x4_to_fp8(c.x, c.y, c.z, c.w);
        *(uint2*)(xq + (size_t)i * 8) = pk;
    } else {
        int region = (b - cvt_blocks) >> 6;
        int idx = ((b - cvt_blocks) & 63) * 256 + threadIdx.x;   // 0..16383
        int k = idx >> 7, c = idx & 127;
        int d = ((k >> 5) * 8 + (c >> 4)) * 512 + ((k >> 3) & 3) * 128 + (c & 15) * 8 + (k & 7);
        if (region == 0) {
            W1p[d] = f2bf(Wl1[idx]);
        } else if (region == 1) {
            W1p[128 * 128 + d] = f2bf(Wr1[idx]);
        } else {
            float v = (c < 64) ? Wl2[k * 64 + c] : Wr2[k * 64 + (c - 64)];
            W2p[d] = f2bf(v);
        }
    }
}

// ---------------------------------------------------------------------------
// Counting sort pass A: bin edges into coarse buckets (dst>>8) with
// block-contiguous run writes (LDS reorder + one atomic per bucket/block).
// ---------------------------------------------------------------------------
__global__ __launch_bounds__(256) void bin_coarse(
    const int* __restrict__ ei, int* __restrict__ cursor,
    unsigned int* __restrict__ coarse, int E, int nb, int cap)
{
    __shared__ int hist[256], lstart[256], gbase[256], wsum[4];
    __shared__ unsigned int staged[4096];
    const int tid = threadIdx.x;
    const int chunkBase = blockIdx.x * 4096;

    hist[tid] = 0;
    __syncthreads();

    unsigned int rec[16]; int pos[16]; int bb[16];
    #pragma unroll
    for (int i = 0; i < 16; ++i) {
        int e = chunkBase + i * 256 + tid;
        if (e < E) {
            int s = ei[e], d = ei[E + e];
            rec[i] = ((unsigned int)d << 16) | (unsigned int)s;
            bb[i]  = d >> 8;
            pos[i] = atomicAdd(&hist[bb[i]], 1);
        } else bb[i] = -1;
    }
    __syncthreads();

    block_excl_scan_256(hist, lstart, wsum, tid);

    if (tid < nb) {
        int c = hist[tid];
        gbase[tid] = c ? atomicAdd(&cursor[tid], c) : 0;
    }
    __syncthreads();

    #pragma unroll
    for (int i = 0; i < 16; ++i)
        if (bb[i] >= 0) staged[lstart[bb[i]] + pos[i]] = rec[i];
    __syncthreads();

    int total = min(4096, E - chunkBase);
    for (int i = tid; i < total; i += 256) {
        unsigned int r = staged[i];
        int b   = (int)(r >> 24);          // dst>>8
        int gp  = gbase[b] + (i - lstart[b]);
        if (gp < cap) coarse[(size_t)b * cap + gp] = r;
    }
}

// ---------------------------------------------------------------------------
// Counting sort pass B: one block per coarse bucket; scatter src (ushort)
// into bucket-owned window; emit deg / row_start.
// ---------------------------------------------------------------------------
__global__ __launch_bounds__(256) void bin_fine(
    const int* __restrict__ cursor, const unsigned int* __restrict__ coarse,
    unsigned short* __restrict__ sorted, int* __restrict__ deg,
    int* __restrict__ row_start, int n, int cap)
{
    __shared__ int hist[256], pstart[256], cur2[256], wsum[4];
    const int b = blockIdx.x, tid = threadIdx.x;
    const int cnt = min(cursor[b], cap);
    const unsigned int* src = coarse + (size_t)b * cap;

    hist[tid] = 0;
    __syncthreads();

    int nIter = (cnt + 255) >> 8;
    for (int i = 0; i < nIter; ++i) {
        int idx = i * 256 + tid;
        if (idx < cnt) atomicAdd(&hist[(src[idx] >> 16) & 255], 1);
    }
    __syncthreads();

    block_excl_scan_256(hist, pstart, wsum, tid);
    cur2[tid] = pstart[tid];
    __syncthreads();

    for (int i = 0; i < nIter; ++i) {
        int idx = i * 256 + tid;
        if (idx < cnt) {
            unsigned int r = src[idx];
            int dl = (r >> 16) & 255;
            int p  = atomicAdd(&cur2[dl], 1);
            sorted[(size_t)b * cap + p] = (unsigned short)(r & 0xFFFFu);
        }
    }

    int node = b * 256 + tid;
    if (node < n) {
        deg[node]       = hist[tid];
        row_start[node] = b * cap + pstart[tid];
    }
}

// ---------------------------------------------------------------------------
// Gather-mean over fp8 x rows (128 B). One wave per node; 8 lanes x 16 B per
// neighbor -> 8 neighbors concurrent. fp32 accumulate, bf16 agg out.
// All __shfl full-wave (tail predicates wave-uniform).
// ---------------------------------------------------------------------------
__global__ __launch_bounds__(256) void agg_gather128(
    const int* __restrict__ row_start, const int* __restrict__ deg,
    const unsigned short* __restrict__ sorted, const unsigned char* __restrict__ xq,
    unsigned short* __restrict__ aggb, int n)
{
    int wave = (blockIdx.x * 256 + threadIdx.x) >> 6;
    int lane = threadIdx.x & 63;
    if (wave >= n) return;
    int sub = lane & 7;        // 16B chunk (16 fp8) of the 128B row
    int oct = lane >> 3;       // which of 8 concurrent neighbors
    int base = row_start[wave];
    int d    = deg[wave];
    float acc[16];
    #pragma unroll
    for (int j = 0; j < 16; ++j) acc[j] = 0.f;

    for (int k0 = 0; k0 < d; k0 += 64) {
        int idx = k0 + lane;
        int mys = (idx < d) ? (int)sorted[base + idx] : 0;
        int kmax = min(64, d - k0);    // wave-uniform
        int ko   = kmax & ~7;
        for (int k = 0; k < ko; k += 8) {
            int s = __shfl(mys, k + oct, 64);
            uint4 raw = ((const uint4*)(xq + (size_t)s * DIN))[sub];
            const unsigned int* w = (const unsigned int*)&raw;
            #pragma unroll
            for (int c = 0; c < 4; ++c) {
                float o4[4];
                fp8x4_to_f32(w[c], o4);
                acc[c*4+0] += o4[0]; acc[c*4+1] += o4[1];
                acc[c*4+2] += o4[2]; acc[c*4+3] += o4[3];
            }
        }
        int rem = kmax - ko;           // wave-uniform, 0..7
        if (rem) {
            int srcl = ko + oct;
            if (srcl >= kmax) srcl = kmax - 1;
            int s = __shfl(mys, srcl, 64);         // full wave
            if (oct < rem) {                       // lane-predicated load/add
                uint4 raw = ((const uint4*)(xq + (size_t)s * DIN))[sub];
                const unsigned int* w = (const unsigned int*)&raw;
                #pragma unroll
                for (int c = 0; c < 4; ++c) {
                    float o4[4];
                    fp8x4_to_f32(w[c], o4);
                    acc[c*4+0] += o4[0]; acc[c*4+1] += o4[1];
                    acc[c*4+2] += o4[2]; acc[c*4+3] += o4[3];
                }
            }
        }
    }
    #pragma unroll
    for (int j = 0; j < 16; ++j) {
        acc[j] += __shfl_xor(acc[j], 32, 64);
        acc[j] += __shfl_xor(acc[j], 16, 64);
        acc[j] += __shfl_xor(acc[j],  8, 64);
    }
    if (oct == 0) {
        float inv = 1.0f / fmaxf((float)d, 1.0f);
        unsigned short t[16];
        #pragma unroll
        for (int j = 0; j < 16; ++j) t[j] = f2bf(acc[j] * inv);
        unsigned short* op = aggb + (size_t)wave * DIN + sub * 16;
        *(uint4*)op = ((uint4*)t)[0];
        *(uint4*)(op + 8) = ((uint4*)t)[1];
    }
}

// ---------------------------------------------------------------------------
// Gather-mean over bf16 P rows (64 cols = 128 B), accumulating into out.
// ---------------------------------------------------------------------------
__global__ __launch_bounds__(256) void agg_gather64_add(
    const int* __restrict__ row_start, const int* __restrict__ deg,
    const unsigned short* __restrict__ sorted, const unsigned short* __restrict__ P,
    float* __restrict__ out, int n)
{
    int wave = (blockIdx.x * 256 + threadIdx.x) >> 6;
    int lane = threadIdx.x & 63;
    if (wave >= n) return;
    int sub = lane & 7;
    int oct = lane >> 3;
    int base = row_start[wave];
    int d    = deg[wave];
    float acc[8];
    #pragma unroll
    for (int j = 0; j < 8; ++j) acc[j] = 0.f;

    for (int k0 = 0; k0 < d; k0 += 64) {
        int idx = k0 + lane;
        int mys = (idx < d) ? (int)sorted[base + idx] : 0;
        int kmax = min(64, d - k0);
        int ko   = kmax & ~7;
        for (int k = 0; k < ko; k += 8) {
            int s = __shfl(mys, k + oct, 64);
            uint4 raw = ((const uint4*)(P + (size_t)s * DOUTC))[sub];
            const unsigned short* u = (const unsigned short*)&raw;
            #pragma unroll
            for (int j = 0; j < 8; ++j) acc[j] += bf2f(u[j]);
        }
        int rem = kmax - ko;
        if (rem) {
            int srcl = ko + oct;
            if (srcl >= kmax) srcl = kmax - 1;
            int s = __shfl(mys, srcl, 64);
            if (oct < rem) {
                uint4 raw = ((const uint4*)(P + (size_t)s * DOUTC))[sub];
                const unsigned short* u = (const unsigned short*)&raw;
                #pragma unroll
                for (int j = 0; j < 8; ++j) acc[j] += bf2f(u[j]);
            }
        }
    }
    #pragma unroll
    for (int j = 0; j < 8; ++j) {
        acc[j] += __shfl_xor(acc[j], 32, 64);
        acc[j] += __shfl_xor(acc[j], 16, 64);
        acc[j] += __shfl_xor(acc[j],  8, 64);
    }
    if (oct == 0) {
        float inv = 1.0f / fmaxf((float)d, 1.0f);
        float* op = out + (size_t)wave * DOUTC + sub * 8;
        float4 c0 = *(float4*)op;
        float4 c1 = *((float4*)op + 1);
        c0.x += acc[0] * inv; c0.y += acc[1] * inv;
        c0.z += acc[2] * inv; c0.w += acc[3] * inv;
        c1.x += acc[4] * inv; c1.y += acc[5] * inv;
        c1.z += acc[6] * inv; c1.w += acc[7] * inv;
        *(float4*)op = c0;
        *((float4*)op + 1) = c1;
    }
}

// ---------------------------------------------------------------------------
// GEMM1 (MFMA bf16): hb = agg@Wl1 + x@Wr1 + b1 (bf16 store), + BN partials
// from the fp32 accumulators.
// ---------------------------------------------------------------------------
__global__ __launch_bounds__(256) void gemm1_mfma(
    const unsigned short* __restrict__ aggb, const unsigned short* __restrict__ xb,
    const unsigned short* __restrict__ W1p, const float* __restrict__ bias,
    unsigned short* __restrict__ hb,
    float* __restrict__ bn_sum, float* __restrict__ bn_sumsq, int n)
{
    __shared__ union {
        unsigned short A[64][136];
        float red[2][4][128];
    } sm;

    const int block_row = blockIdx.x * 64;
    const int tid  = threadIdx.x;
    const int wave = tid >> 6;
    const int lane = tid & 63;
    const int q    = lane >> 4;
    const int m16  = lane & 15;

    f32x4 acc[8];
    #pragma unroll
    for (int nt = 0; nt < 8; ++nt) acc[nt] = (f32x4){0.f, 0.f, 0.f, 0.f};

    #pragma unroll
    for (int phase = 0; phase < 2; ++phase) {
        const unsigned short* src = phase ? xb : aggb;
        #pragma unroll
        for (int i = 0; i < 4; ++i) {
            int idx = tid + i * 256;
            int r   = idx >> 4;
            int c16 = idx & 15;
            int g   = block_row + r;
            uint4 v = {0u, 0u, 0u, 0u};
            if (g < n) v = ((const uint4*)(src + (size_t)g * DIN))[c16];
            *(uint4*)&sm.A[r][c16 * 8] = v;
        }
        __syncthreads();

        #pragma unroll
        for (int ks = 0; ks < 4; ++ks) {
            bf16x8 a = *(const bf16x8*)&sm.A[wave * 16 + m16][ks * 32 + q * 8];
            const unsigned short* wp = W1p + (size_t)(phase * 4 + ks) * 8 * 512;
            #pragma unroll
            for (int nt = 0; nt < 8; ++nt) {
                bf16x8 b = *(const bf16x8*)(wp + nt * 512 + lane * 8);
                acc[nt] = __builtin_amdgcn_mfma_f32_16x16x32_bf16(a, b, acc[nt], 0, 0, 0);
            }
        }
        __syncthreads();
    }

    float psum[8], psq[8];
    #pragma unroll
    for (int nt = 0; nt < 8; ++nt) {
        int col = nt * 16 + m16;
        float bv = bias[col];
        float s = 0.f, ssq = 0.f;
        #pragma unroll
        for (int reg = 0; reg < 4; ++reg) {
            int g = block_row + wave * 16 + q * 4 + reg;
            float v = acc[nt][reg] + bv;
            if (g < n) {
                hb[(size_t)g * DH + col] = f2bf(v);
                s += v; ssq += v * v;
            }
        }
        psum[nt] = s; psq[nt] = ssq;
    }
    #pragma unroll
    for (int nt = 0; nt < 8; ++nt) {
        psum[nt] += __shfl_xor(psum[nt], 16, 64);
        psum[nt] += __shfl_xor(psum[nt], 32, 64);
        psq[nt]  += __shfl_xor(psq[nt], 16, 64);
        psq[nt]  += __shfl_xor(psq[nt], 32, 64);
    }
    if (lane < 16) {
        #pragma unroll
        for (int nt = 0; nt < 8; ++nt) {
            sm.red[0][wave][nt * 16 + lane] = psum[nt];
            sm.red[1][wave][nt * 16 + lane] = psq[nt];
        }
    }
    __syncthreads();
    if (tid < 128) {
        float s = sm.red[0][0][tid] + sm.red[0][1][tid] +
                  sm.red[0][2][tid] + sm.red[0][3][tid];
        float ssq = sm.red[1][0][tid] + sm.red[1][1][tid] +
                    sm.red[1][2][tid] + sm.red[1][3][tid];
        atomicAdd(&bn_sum[tid], s);
        atomicAdd(&bn_sumsq[tid], ssq);
    }
}

// ---------------------------------------------------------------------------
// GEMM2 (MFMA bf16), BN finalize + BN+ReLU fused into the staging load:
// scale/shift computed per-block from bn_sum/bn_sumsq (128 rsqrt/block).
// a = relu(hb*scale+shift); P = a@Wl2 (bf16), out = a@Wr2 + b2 (fp32).
// ---------------------------------------------------------------------------
__global__ __launch_bounds__(256) void gemm2p_mfma(
    const unsigned short* __restrict__ hb,
    const float* __restrict__ bn_sum, const float* __restrict__ bn_sumsq,
    const float* __restrict__ gamma, const float* __restrict__ beta,
    const unsigned short* __restrict__ W2p, const float* __restrict__ bias,
    unsigned short* __restrict__ P, float* __restrict__ out, int n)
{
    __shared__ unsigned short A[64][136];
    __shared__ float s_scale[128], s_shift[128];

    const int block_row = blockIdx.x * 64;
    const int tid  = threadIdx.x;
    const int wave = tid >> 6;
    const int lane = tid & 63;
    const int q    = lane >> 4;
    const int m16  = lane & 15;

    if (tid < 128) {
        float invN = 1.0f / (float)n;
        float mu  = bn_sum[tid] * invN;
        float var = bn_sumsq[tid] * invN - mu * mu;
        float sc  = gamma[tid] * rsqrtf(var + BN_EPS);
        s_scale[tid] = sc;
        s_shift[tid] = beta[tid] - mu * sc;
    }
    __syncthreads();

    // stage relu(hb*scale+shift) as bf16: 64 rows x 16 uint4 chunks (8 bf16)
    #pragma unroll
    for (int i = 0; i < 4; ++i) {
        int idx = tid + i * 256;
        int r   = idx >> 4;
        int c16 = idx & 15;
        int g   = block_row + r;
        unsigned short t[8] = {0,0,0,0,0,0,0,0};
        if (g < n) {
            uint4 raw = ((const uint4*)(hb + (size_t)g * DH))[c16];
            const unsigned short* u = (const unsigned short*)&raw;
            #pragma unroll
            for (int j = 0; j < 8; ++j) {
                int col = c16 * 8 + j;
                float v = bf2f(u[j]) * s_scale[col] + s_shift[col];
                t[j] = f2bf(fmaxf(v, 0.f));
            }
        }
        *(uint4*)&A[r][c16 * 8] = *(uint4*)t;
    }
    __syncthreads();

    f32x4 acc[8];
    #pragma unroll
    for (int nt = 0; nt < 8; ++nt) acc[nt] = (f32x4){0.f, 0.f, 0.f, 0.f};

    #pragma unroll
    for (int ks = 0; ks < 4; ++ks) {
        bf16x8 a = *(const bf16x8*)&A[wave * 16 + m16][ks * 32 + q * 8];
        const unsigned short* wp = W2p + (size_t)ks * 8 * 512;
        #pragma unroll
        for (int nt = 0; nt < 8; ++nt) {
            bf16x8 b = *(const bf16x8*)(wp + nt * 512 + lane * 8);
            acc[nt] = __builtin_amdgcn_mfma_f32_16x16x32_bf16(a, b, acc[nt], 0, 0, 0);
        }
    }

    #pragma unroll
    for (int nt = 0; nt < 4; ++nt) {
        int col = nt * 16 + m16;
        #pragma unroll
        for (int reg = 0; reg < 4; ++reg) {
            int g = block_row + wave * 16 + q * 4 + reg;
            if (g < n) P[(size_t)g * DOUTC + col] = f2bf(acc[nt][reg]);
        }
    }
    #pragma unroll
    for (int nt = 4; nt < 8; ++nt) {
        int col = (nt - 4) * 16 + m16;
        float bv = bias[col];
        #pragma unroll
        for (int reg = 0; reg < 4; ++reg) {
            int g = block_row + wave * 16 + q * 4 + reg;
            if (g < n) out[(size_t)g * DOUTC + col] = acc[nt][reg] + bv;
        }
    }
}

// ---------------------------------------------------------------------------
extern "C" void kernel_launch(void* const* d_in, const int* in_sizes, int n_in,
                              void* d_out, int out_size, void* d_ws, size_t ws_size,
                              hipStream_t stream)
{
    const float* x     = (const float*)d_in[0];
    const int*   ei    = (const int*)  d_in[1];
    const float* Wl1   = (const float*)d_in[2];
    const float* Wr1   = (const float*)d_in[3];
    const float* b1    = (const float*)d_in[4];
    const float* gamma = (const float*)d_in[5];
    const float* beta  = (const float*)d_in[6];
    const float* Wl2   = (const float*)d_in[7];
    const float* Wr2   = (const float*)d_in[8];
    const float* b2    = (const float*)d_in[9];
    float*       out   = (float*)d_out;

    const int N = in_sizes[0] / DIN;      // 50000
    const int E = in_sizes[1] / 2;        // 800000

    const int NB  = (N + 255) >> 8;                       // coarse buckets
    int cap = (E / NB) * 3 / 2 + 256;
    cap = (cap + 255) & ~255;

    // workspace layout (segments 16B-aligned)
    float* bn_sum   = (float*)d_ws;                       // 128
    float* bn_sumsq = bn_sum + DH;                        // 128
    int* cursor     = (int*)(bn_sumsq + DH);              // 256
    int* deg        = cursor + 256;                       // N
    int* row_start  = deg + N;                            // N
    unsigned int* coarse   = (unsigned int*)(row_start + N);           // NB*cap
    unsigned short* sorted = (unsigned short*)(coarse + (size_t)NB * cap);
    unsigned short* hb     = sorted + (size_t)NB * cap;   // N*128 bf16
    unsigned short* aggb   = hb + (size_t)N * DH;         // N*128 bf16
    unsigned short* xb     = aggb + (size_t)N * DIN;      // N*128 bf16
    unsigned short* P      = xb + (size_t)N * DIN;        // N*64 bf16
    unsigned short* W1p    = P + (size_t)N * DOUTC;       // 256*128 bf16
    unsigned short* W2p    = W1p + 256 * 128;             // 128*128 bf16
    unsigned char*  xq     = (unsigned char*)(W2p + 128 * 128); // N*128 fp8

    // zero bn sums + coarse cursors (contiguous: 128+128 f32 + 256 i32)
    hipMemsetAsync(bn_sum, 0, (2 * DH + 256) * sizeof(float), stream);

    dim3 blk(256);
    const int binA_blocks = (E + 4095) / 4096;
    const int wave_blocks = (N + 3) / 4;
    const int gemm_blocks = (N + 63) / 64;
    const int cvt_blocks  = (N * DIN / 8 + 255) / 256;

    // ---- fused conversions + weight packing ----
    cvtpack_kernel<<<cvt_blocks + 192, blk, 0, stream>>>(
        x, xb, xq, Wl1, Wr1, Wl2, Wr2, W1p, W2p, N * DIN / 8, cvt_blocks);

    // ---- CSR build: two-pass LDS counting sort ----
    bin_coarse<<<binA_blocks, blk, 0, stream>>>(ei, cursor, coarse, E, NB, cap);
    bin_fine<<<NB, blk, 0, stream>>>(cursor, coarse, sorted, deg, row_start, N, cap);

    // ---- layer 1 ----
    agg_gather128<<<wave_blocks, blk, 0, stream>>>(row_start, deg, sorted,
                                                   xq, aggb, N);
    gemm1_mfma<<<gemm_blocks, blk, 0, stream>>>(aggb, xb, W1p, b1, hb,
                                                bn_sum, bn_sumsq, N);

    // ---- layer 2 (BN finalize + BN+ReLU fused; project-then-gather) ----
    gemm2p_mfma<<<gemm_blocks, blk, 0, stream>>>(hb, bn_sum, bn_sumsq,
                                                 gamma, beta, W2p, b2,
                                                 P, out, N);
    agg_gather64_add<<<wave_blocks, blk, 0, stream>>>(row_start, deg, sorted,
                                                      P, out, N);
}

// Round 9
// 214.308 us; speedup vs baseline: 13.9040x; 1.0328x over previous
//
#include <hip/hip_runtime.h>
#include <hip/hip_bf16.h>
#include <hip/hip_fp8.h>

#define DIN   128
#define DH    128
#define DOUTC 64
#define BN_EPS 1e-5f

typedef __attribute__((ext_vector_type(8))) short bf16x8;
typedef __attribute__((ext_vector_type(4))) float f32x4;
typedef __attribute__((ext_vector_type(2))) float f32x2;

#ifndef __has_builtin
#define __has_builtin(x) 0
#endif
#if __has_builtin(__builtin_amdgcn_cvt_pk_f32_fp8) && __has_builtin(__builtin_amdgcn_cvt_pk_fp8_f32)
#define HW_FP8 1
#else
#define HW_FP8 0
#endif

__device__ inline unsigned short f2bf(float f) {
    __hip_bfloat16 b = __float2bfloat16(f);
    return *reinterpret_cast<unsigned short*>(&b);
}
__device__ inline float bf2f(unsigned short u) {
    return __uint_as_float(((unsigned int)u) << 16);
}
__device__ inline void fp8x4_to_f32(unsigned int w, float* o) {
#if HW_FP8
    f32x2 lo = __builtin_amdgcn_cvt_pk_f32_fp8((int)w, false);
    f32x2 hi = __builtin_amdgcn_cvt_pk_f32_fp8((int)w, true);
    o[0] = lo.x; o[1] = lo.y; o[2] = hi.x; o[3] = hi.y;
#else
    #pragma unroll
    for (int c = 0; c < 4; ++c) {
        __hip_fp8_e4m3 q; q.__x = (__hip_fp8_storage_t)((w >> (8 * c)) & 0xFF);
        o[c] = (float)q;
    }
#endif
}
__device__ inline unsigned int f32x4_to_fp8(float a, float b, float c, float d) {
#if HW_FP8
    int p = __builtin_amdgcn_cvt_pk_fp8_f32(a, b, 0, false);
    p = __builtin_amdgcn_cvt_pk_fp8_f32(c, d, p, true);
    return (unsigned int)p;
#else
    __hip_fp8_e4m3 qa(a), qb(b), qc(c), qd(d);
    return (unsigned int)qa.__x | ((unsigned int)qb.__x << 8) |
           ((unsigned int)qc.__x << 16) | ((unsigned int)qd.__x << 24);
#endif
}

// ---------------------------------------------------------------------------
// Exclusive prefix scan over 256 LDS ints (all 256 threads must call).
// ---------------------------------------------------------------------------
__device__ inline void block_excl_scan_256(const int* __restrict__ arr,
                                           int* __restrict__ excl,
                                           int* __restrict__ wsum, int tid)
{
    int lane = tid & 63, w = tid >> 6;
    int v = arr[tid];
    int inc = v;
    #pragma unroll
    for (int off = 1; off < 64; off <<= 1) {
        int t = __shfl_up(inc, off, 64);
        if (lane >= off) inc += t;
    }
    if (lane == 63) wsum[w] = inc;
    __syncthreads();
    if (tid == 0) {
        int s = 0;
        #pragma unroll
        for (int i = 0; i < 4; ++i) { int t = wsum[i]; wsum[i] = s; s += t; }
    }
    __syncthreads();
    excl[tid] = inc - v + wsum[w];
    __syncthreads();
}

// ---------------------------------------------------------------------------
// prep_kernel — three independent block ranges:
//   [0, cvtB)              : x -> xb (bf16) and xq (fp8 e4m3)
//   [cvtB, cvtB+192)       : pack Wl1 / Wr1 / [Wl2|Wr2] into MFMA B-frag order
//   [cvtB+192, cvtB+192+nb): bin_coarse — counting-sort pass A (dst>>8),
//                            block-contiguous run writes (no line bouncing)
// B-frag pack: dst[(k/32*8 + c/16)*512 + ((k/8)&3)*128 + (c&15)*8 + (k&7)].
// ---------------------------------------------------------------------------
__global__ __launch_bounds__(256) void prep_kernel(
    const float* __restrict__ x, unsigned short* __restrict__ xb,
    unsigned char* __restrict__ xq,
    const float* __restrict__ Wl1, const float* __restrict__ Wr1,
    const float* __restrict__ Wl2, const float* __restrict__ Wr2,
    unsigned short* __restrict__ W1p, unsigned short* __restrict__ W2p,
    const int* __restrict__ ei, int* __restrict__ cursor,
    unsigned int* __restrict__ coarse,
    int total8, int cvtB, int E, int nb, int cap)
{
    __shared__ int hist[256], lstart[256], gbase[256], wsum[4];
    __shared__ unsigned int staged[4096];
    const int b = blockIdx.x;
    const int tid = threadIdx.x;

    if (b < cvtB) {
        int i = b * 256 + tid;
        if (i >= total8) return;
        float4 a = ((const float4*)x)[2 * i];
        float4 c = ((const float4*)x)[2 * i + 1];
        unsigned short t[8];
        t[0]=f2bf(a.x); t[1]=f2bf(a.y); t[2]=f2bf(a.z); t[3]=f2bf(a.w);
        t[4]=f2bf(c.x); t[5]=f2bf(c.y); t[6]=f2bf(c.z); t[7]=f2bf(c.w);
        *(uint4*)(xb + (size_t)i * 8) = *(uint4*)t;
        uint2 pk;
        pk.x = f32x4_to_fp8(a.x, a.y, a.z, a.w);
        pk.y = f32x4_to_fp8(c.x, c.y, c.z, c.w);
        *(uint2*)(xq + (size_t)i * 8) = pk;
        return;
    }
    if (b < cvtB + 192) {
        int region = (b - cvtB) >> 6;
        int idx = ((b - cvtB) & 63) * 256 + tid;   // 0..16383
        int k = idx >> 7, c = idx & 127;
        int d = ((k >> 5) * 8 + (c >> 4)) * 512 + ((k >> 3) & 3) * 128 + (c & 15) * 8 + (k & 7);
        if (region == 0)      W1p[d] = f2bf(Wl1[idx]);
        else if (region == 1) W1p[128 * 128 + d] = f2bf(Wr1[idx]);
        else {
            float v = (c < 64) ? Wl2[k * 64 + c] : Wr2[k * 64 + (c - 64)];
            W2p[d] = f2bf(v);
        }
        return;
    }

    // ---- bin_coarse ----
    const int chunkBase = (b - cvtB - 192) * 4096;
    hist[tid] = 0;
    __syncthreads();

    unsigned int rec[16]; int pos[16]; int bb[16];
    #pragma unroll
    for (int i = 0; i < 16; ++i) {
        int e = chunkBase + i * 256 + tid;
        if (e < E) {
            int s = ei[e], d = ei[E + e];
            rec[i] = ((unsigned int)d << 16) | (unsigned int)s;
            bb[i]  = d >> 8;
            pos[i] = atomicAdd(&hist[bb[i]], 1);
        } else bb[i] = -1;
    }
    __syncthreads();

    block_excl_scan_256(hist, lstart, wsum, tid);

    if (tid < nb) {
        int c = hist[tid];
        gbase[tid] = c ? atomicAdd(&cursor[tid], c) : 0;
    }
    __syncthreads();

    #pragma unroll
    for (int i = 0; i < 16; ++i)
        if (bb[i] >= 0) staged[lstart[bb[i]] + pos[i]] = rec[i];
    __syncthreads();

    int total = min(4096, E - chunkBase);
    for (int i = tid; i < total; i += 256) {
        unsigned int r = staged[i];
        int bk  = (int)(r >> 24);          // dst>>8
        int gp  = gbase[bk] + (i - lstart[bk]);
        if (gp < cap) coarse[(size_t)bk * cap + gp] = r;
    }
}

// ---------------------------------------------------------------------------
// Counting sort pass B: one block per coarse bucket; scatter src (ushort)
// into bucket-owned window; emit deg / row_start.
// ---------------------------------------------------------------------------
__global__ __launch_bounds__(256) void bin_fine(
    const int* __restrict__ cursor, const unsigned int* __restrict__ coarse,
    unsigned short* __restrict__ sorted, int* __restrict__ deg,
    int* __restrict__ row_start, int n, int cap)
{
    __shared__ int hist[256], pstart[256], cur2[256], wsum[4];
    const int b = blockIdx.x, tid = threadIdx.x;
    const int cnt = min(cursor[b], cap);
    const unsigned int* src = coarse + (size_t)b * cap;

    hist[tid] = 0;
    __syncthreads();

    int nIter = (cnt + 255) >> 8;
    for (int i = 0; i < nIter; ++i) {
        int idx = i * 256 + tid;
        if (idx < cnt) atomicAdd(&hist[(src[idx] >> 16) & 255], 1);
    }
    __syncthreads();

    block_excl_scan_256(hist, pstart, wsum, tid);
    cur2[tid] = pstart[tid];
    __syncthreads();

    for (int i = 0; i < nIter; ++i) {
        int idx = i * 256 + tid;
        if (idx < cnt) {
            unsigned int r = src[idx];
            int dl = (r >> 16) & 255;
            int p  = atomicAdd(&cur2[dl], 1);
            sorted[(size_t)b * cap + p] = (unsigned short)(r & 0xFFFFu);
        }
    }

    int node = b * 256 + tid;
    if (node < n) {
        deg[node]       = hist[tid];
        row_start[node] = b * cap + pstart[tid];
    }
}

// ---------------------------------------------------------------------------
// GEMM1 fused with layer-1 gather:
//   G-tile = per-row gather-mean of fp8 x-neighbors (shfl-free: 8 rows/wave,
//            8 lanes/row, each lane owns a 16B slice and loops its row's
//            neighbor list directly) -> bf16 LDS
//   X-tile = own x rows (bf16)
//   MFMA: acc += G@Wl1 + X@Wr1  (each wave reads ONLY its own 16 rows ->
//   no barrier between LDS fill and MFMA)
//   Epilogue: +b1, hb (bf16) store, BN sum/sumsq partials.
// ---------------------------------------------------------------------------
__global__ __launch_bounds__(256) void gemm1_fused(
    const unsigned char* __restrict__ xq, const unsigned short* __restrict__ xb,
    const int* __restrict__ row_start, const int* __restrict__ deg,
    const unsigned short* __restrict__ sorted,
    const unsigned short* __restrict__ W1p, const float* __restrict__ bias,
    unsigned short* __restrict__ hb,
    float* __restrict__ bn_sum, float* __restrict__ bn_sumsq, int n)
{
    __shared__ unsigned short X[64][136];
    __shared__ unsigned short G[64][136];
    __shared__ float red[2][4][128];

    const int block_row = blockIdx.x * 64;
    const int tid  = threadIdx.x;
    const int wave = tid >> 6;
    const int lane = tid & 63;
    const int q    = lane >> 4;
    const int m16  = lane & 15;

    // ---- stage own 16 x rows (bf16): lane -> row wave*16+(lane>>2), 4 chunks
    {
        int lr = wave * 16 + (lane >> 2);
        int g  = block_row + lr;
        #pragma unroll
        for (int i = 0; i < 4; ++i) {
            int c16 = (lane & 3) + 4 * i;
            uint4 v = {0u, 0u, 0u, 0u};
            if (g < n) v = ((const uint4*)(xb + (size_t)g * DIN))[c16];
            *(uint4*)&X[lr][c16 * 8] = v;
        }
    }

    // ---- gather own 16 rows into G: 2 groups of 8 rows, 8 lanes/row ----
    {
        int sub = lane & 7, oct = lane >> 3;
        #pragma unroll
        for (int grp = 0; grp < 2; ++grp) {
            int lr = wave * 16 + grp * 8 + oct;
            int g  = block_row + lr;
            float acc[16];
            #pragma unroll
            for (int j = 0; j < 16; ++j) acc[j] = 0.f;
            int d = 0;
            if (g < n) {
                int base = row_start[g];
                d = deg[g];
                for (int t = 0; t < d; ++t) {
                    int s = (int)sorted[base + t];
                    uint4 raw = ((const uint4*)(xq + (size_t)s * DIN))[sub];
                    const unsigned int* w = (const unsigned int*)&raw;
                    #pragma unroll
                    for (int c = 0; c < 4; ++c) {
                        float o4[4];
                        fp8x4_to_f32(w[c], o4);
                        acc[c*4+0] += o4[0]; acc[c*4+1] += o4[1];
                        acc[c*4+2] += o4[2]; acc[c*4+3] += o4[3];
                    }
                }
            }
            float inv = 1.0f / fmaxf((float)d, 1.0f);
            unsigned short t16[16];
            #pragma unroll
            for (int j = 0; j < 16; ++j) t16[j] = f2bf(acc[j] * inv);
            *(uint4*)&G[lr][sub * 16]     = ((uint4*)t16)[0];
            *(uint4*)&G[lr][sub * 16 + 8] = ((uint4*)t16)[1];
        }
    }
    // no __syncthreads needed: each wave reads only rows it wrote.

    f32x4 acc[8];
    #pragma unroll
    for (int nt = 0; nt < 8; ++nt) acc[nt] = (f32x4){0.f, 0.f, 0.f, 0.f};

    #pragma unroll
    for (int ks = 0; ks < 4; ++ks) {
        bf16x8 ag = *(const bf16x8*)&G[wave * 16 + m16][ks * 32 + q * 8];
        const unsigned short* wp0 = W1p + (size_t)ks * 8 * 512;          // Wl1
        #pragma unroll
        for (int nt = 0; nt < 8; ++nt) {
            bf16x8 b = *(const bf16x8*)(wp0 + nt * 512 + lane * 8);
            acc[nt] = __builtin_amdgcn_mfma_f32_16x16x32_bf16(ag, b, acc[nt], 0, 0, 0);
        }
        bf16x8 ax = *(const bf16x8*)&X[wave * 16 + m16][ks * 32 + q * 8];
        const unsigned short* wp1 = W1p + (size_t)(4 + ks) * 8 * 512;    // Wr1
        #pragma unroll
        for (int nt = 0; nt < 8; ++nt) {
            bf16x8 b = *(const bf16x8*)(wp1 + nt * 512 + lane * 8);
            acc[nt] = __builtin_amdgcn_mfma_f32_16x16x32_bf16(ax, b, acc[nt], 0, 0, 0);
        }
    }

    // ---- epilogue: bias, hb store, BN partials ----
    float psum[8], psq[8];
    #pragma unroll
    for (int nt = 0; nt < 8; ++nt) {
        int col = nt * 16 + m16;
        float bv = bias[col];
        float s = 0.f, ssq = 0.f;
        #pragma unroll
        for (int reg = 0; reg < 4; ++reg) {
            int g = block_row + wave * 16 + q * 4 + reg;
            float v = acc[nt][reg] + bv;
            if (g < n) {
                hb[(size_t)g * DH + col] = f2bf(v);
                s += v; ssq += v * v;
            }
        }
        psum[nt] = s; psq[nt] = ssq;
    }
    #pragma unroll
    for (int nt = 0; nt < 8; ++nt) {
        psum[nt] += __shfl_xor(psum[nt], 16, 64);
        psum[nt] += __shfl_xor(psum[nt], 32, 64);
        psq[nt]  += __shfl_xor(psq[nt], 16, 64);
        psq[nt]  += __shfl_xor(psq[nt], 32, 64);
    }
    if (lane < 16) {
        #pragma unroll
        for (int nt = 0; nt < 8; ++nt) {
            red[0][wave][nt * 16 + lane] = psum[nt];
            red[1][wave][nt * 16 + lane] = psq[nt];
        }
    }
    __syncthreads();
    if (tid < 128) {
        float s = red[0][0][tid] + red[0][1][tid] + red[0][2][tid] + red[0][3][tid];
        float ssq = red[1][0][tid] + red[1][1][tid] + red[1][2][tid] + red[1][3][tid];
        atomicAdd(&bn_sum[tid], s);
        atomicAdd(&bn_sumsq[tid], ssq);
    }
}

// ---------------------------------------------------------------------------
// GEMM2 (MFMA bf16): BN finalize in LDS, per-wave staging of
// a = relu(hb*scale+shift), single barrier, then MFMA.
// cols 0..63 -> P = a@Wl2 (bf16), cols 64..127 -> out = a@Wr2 + b2 (fp32).
// ---------------------------------------------------------------------------
__global__ __launch_bounds__(256) void gemm2p_mfma(
    const unsigned short* __restrict__ hb,
    const float* __restrict__ bn_sum, const float* __restrict__ bn_sumsq,
    const float* __restrict__ gamma, const float* __restrict__ beta,
    const unsigned short* __restrict__ W2p, const float* __restrict__ bias,
    unsigned short* __restrict__ P, float* __restrict__ out, int n)
{
    __shared__ unsigned short A[64][136];
    __shared__ float s_scale[128], s_shift[128];

    const int block_row = blockIdx.x * 64;
    const int tid  = threadIdx.x;
    const int wave = tid >> 6;
    const int lane = tid & 63;
    const int q    = lane >> 4;
    const int m16  = lane & 15;

    if (tid < 128) {
        float invN = 1.0f / (float)n;
        float mu  = bn_sum[tid] * invN;
        float var = bn_sumsq[tid] * invN - mu * mu;
        float sc  = gamma[tid] * rsqrtf(var + BN_EPS);
        s_scale[tid] = sc;
        s_shift[tid] = beta[tid] - mu * sc;
    }
    __syncthreads();

    // per-wave staging of own 16 rows
    {
        int lr = wave * 16 + (lane >> 2);
        int g  = block_row + lr;
        #pragma unroll
        for (int i = 0; i < 4; ++i) {
            int c16 = (lane & 3) + 4 * i;
            unsigned short t[8] = {0,0,0,0,0,0,0,0};
            if (g < n) {
                uint4 raw = ((const uint4*)(hb + (size_t)g * DH))[c16];
                const unsigned short* u = (const unsigned short*)&raw;
                #pragma unroll
                for (int j = 0; j < 8; ++j) {
                    int col = c16 * 8 + j;
                    float v = bf2f(u[j]) * s_scale[col] + s_shift[col];
                    t[j] = f2bf(fmaxf(v, 0.f));
                }
            }
            *(uint4*)&A[lr][c16 * 8] = *(uint4*)t;
        }
    }
    // no second barrier: wave reads only its own rows.

    f32x4 acc[8];
    #pragma unroll
    for (int nt = 0; nt < 8; ++nt) acc[nt] = (f32x4){0.f, 0.f, 0.f, 0.f};

    #pragma unroll
    for (int ks = 0; ks < 4; ++ks) {
        bf16x8 a = *(const bf16x8*)&A[wave * 16 + m16][ks * 32 + q * 8];
        const unsigned short* wp = W2p + (size_t)ks * 8 * 512;
        #pragma unroll
        for (int nt = 0; nt < 8; ++nt) {
            bf16x8 b = *(const bf16x8*)(wp + nt * 512 + lane * 8);
            acc[nt] = __builtin_amdgcn_mfma_f32_16x16x32_bf16(a, b, acc[nt], 0, 0, 0);
        }
    }

    #pragma unroll
    for (int nt = 0; nt < 4; ++nt) {
        int col = nt * 16 + m16;
        #pragma unroll
        for (int reg = 0; reg < 4; ++reg) {
            int g = block_row + wave * 16 + q * 4 + reg;
            if (g < n) P[(size_t)g * DOUTC + col] = f2bf(acc[nt][reg]);
        }
    }
    #pragma unroll
    for (int nt = 4; nt < 8; ++nt) {
        int col = (nt - 4) * 16 + m16;
        float bv = bias[col];
        #pragma unroll
        for (int reg = 0; reg < 4; ++reg) {
            int g = block_row + wave * 16 + q * 4 + reg;
            if (g < n) out[(size_t)g * DOUTC + col] = acc[nt][reg] + bv;
        }
    }
}

// ---------------------------------------------------------------------------
// Layer-2 gather-mean over bf16 P rows, shfl-free: 8 rows/wave, 8 lanes/row,
// each lane owns a 16B slice, loops its row's neighbor list, and updates its
// own 32B of out. No cross-lane ops at all.
// ---------------------------------------------------------------------------
__global__ __launch_bounds__(256) void agg_gather64_add(
    const int* __restrict__ row_start, const int* __restrict__ deg,
    const unsigned short* __restrict__ sorted, const unsigned short* __restrict__ P,
    float* __restrict__ out, int n)
{
    int wid  = (blockIdx.x * 256 + threadIdx.x) >> 6;
    int lane = threadIdx.x & 63;
    int sub = lane & 7, oct = lane >> 3;
    int r = wid * 8 + oct;
    if (r >= n) return;

    float acc[8];
    #pragma unroll
    for (int j = 0; j < 8; ++j) acc[j] = 0.f;

    int base = row_start[r];
    int d    = deg[r];
    for (int t = 0; t < d; ++t) {
        int s = (int)sorted[base + t];
        uint4 raw = ((const uint4*)(P + (size_t)s * DOUTC))[sub];
        const unsigned short* u = (const unsigned short*)&raw;
        #pragma unroll
        for (int j = 0; j < 8; ++j) acc[j] += bf2f(u[j]);
    }
    float inv = 1.0f / fmaxf((float)d, 1.0f);
    float* op = out + (size_t)r * DOUTC + sub * 8;
    float4 c0 = *(float4*)op;
    float4 c1 = *((float4*)op + 1);
    c0.x += acc[0] * inv; c0.y += acc[1] * inv;
    c0.z += acc[2] * inv; c0.w += acc[3] * inv;
    c1.x += acc[4] * inv; c1.y += acc[5] * inv;
    c1.z += acc[6] * inv; c1.w += acc[7] * inv;
    *(float4*)op = c0;
    *((float4*)op + 1) = c1;
}

// ---------------------------------------------------------------------------
extern "C" void kernel_launch(void* const* d_in, const int* in_sizes, int n_in,
                              void* d_out, int out_size, void* d_ws, size_t ws_size,
                              hipStream_t stream)
{
    const float* x     = (const float*)d_in[0];
    const int*   ei    = (const int*)  d_in[1];
    const float* Wl1   = (const float*)d_in[2];
    const float* Wr1   = (const float*)d_in[3];
    const float* b1    = (const float*)d_in[4];
    const float* gamma = (const float*)d_in[5];
    const float* beta  = (const float*)d_in[6];
    const float* Wl2   = (const float*)d_in[7];
    const float* Wr2   = (const float*)d_in[8];
    const float* b2    = (const float*)d_in[9];
    float*       out   = (float*)d_out;

    const int N = in_sizes[0] / DIN;      // 50000
    const int E = in_sizes[1] / 2;        // 800000

    const int NB  = (N + 255) >> 8;                       // coarse buckets
    int cap = (E / NB) * 3 / 2 + 256;
    cap = (cap + 255) & ~255;

    // workspace layout (segments 16B-aligned)
    float* bn_sum   = (float*)d_ws;                       // 128
    float* bn_sumsq = bn_sum + DH;                        // 128
    int* cursor     = (int*)(bn_sumsq + DH);              // 256
    int* deg        = cursor + 256;                       // N
    int* row_start  = deg + N;                            // N
    unsigned int* coarse   = (unsigned int*)(row_start + N);            // NB*cap
    unsigned short* sorted = (unsigned short*)(coarse + (size_t)NB * cap);
    unsigned short* hb     = sorted + (size_t)NB * cap;   // N*128 bf16
    unsigned short* xb     = hb + (size_t)N * DH;         // N*128 bf16
    unsigned short* P      = xb + (size_t)N * DIN;        // N*64 bf16
    unsigned short* W1p    = P + (size_t)N * DOUTC;       // 256*128 bf16
    unsigned short* W2p    = W1p + 256 * 128;             // 128*128 bf16
    unsigned char*  xq     = (unsigned char*)(W2p + 128 * 128); // N*128 fp8

    // zero bn sums + coarse cursors (contiguous: 256 f32 + 256 i32)
    hipMemsetAsync(bn_sum, 0, (2 * DH + 256) * sizeof(float), stream);

    dim3 blk(256);
    const int cvtB        = (N * DIN / 8 + 255) / 256;        // 3125
    const int binA_blocks = (E + 4095) / 4096;                // 196
    const int gemm_blocks = (N + 63) / 64;
    const int g64_blocks  = ((N + 7) / 8 + 3) / 4;

    // ---- prep: x-convert | weight-pack | coarse-bin (one launch) ----
    prep_kernel<<<cvtB + 192 + binA_blocks, blk, 0, stream>>>(
        x, xb, xq, Wl1, Wr1, Wl2, Wr2, W1p, W2p,
        ei, cursor, coarse, N * DIN / 8, cvtB, E, NB, cap);

    // ---- counting sort pass B ----
    bin_fine<<<NB, blk, 0, stream>>>(cursor, coarse, sorted, deg, row_start, N, cap);

    // ---- layer 1: fused gather + GEMM + BN partials ----
    gemm1_fused<<<gemm_blocks, blk, 0, stream>>>(xq, xb, row_start, deg, sorted,
                                                 W1p, b1, hb, bn_sum, bn_sumsq, N);

    // ---- layer 2: BN finalize + ReLU + project ----
    gemm2p_mfma<<<gemm_blocks, blk, 0, stream>>>(hb, bn_sum, bn_sumsq,
                                                 gamma, beta, W2p, b2, P, out, N);

    // ---- layer 2 aggregation ----
    agg_gather64_add<<<g64_blocks, blk, 0, stream>>>(row_start, deg, sorted,
                                                     P, out, N);
}

// Round 10
// 209.083 us; speedup vs baseline: 14.2514x; 1.0250x over previous
//
#include <hip/hip_runtime.h>
#include <hip/hip_bf16.h>
#include <hip/hip_fp8.h>

#define DIN   128
#define DH    128
#define DOUTC 64
#define BN_EPS 1e-5f

typedef __attribute__((ext_vector_type(8))) short bf16x8;
typedef __attribute__((ext_vector_type(4))) float f32x4;
typedef __attribute__((ext_vector_type(2))) float f32x2;

#ifndef __has_builtin
#define __has_builtin(x) 0
#endif
#if __has_builtin(__builtin_amdgcn_cvt_pk_f32_fp8) && __has_builtin(__builtin_amdgcn_cvt_pk_fp8_f32)
#define HW_FP8 1
#else
#define HW_FP8 0
#endif

__device__ inline unsigned short f2bf(float f) {
    __hip_bfloat16 b = __float2bfloat16(f);
    return *reinterpret_cast<unsigned short*>(&b);
}
__device__ inline float bf2f(unsigned short u) {
    return __uint_as_float(((unsigned int)u) << 16);
}
__device__ inline void fp8x4_to_f32(unsigned int w, float* o) {
#if HW_FP8
    f32x2 lo = __builtin_amdgcn_cvt_pk_f32_fp8((int)w, false);
    f32x2 hi = __builtin_amdgcn_cvt_pk_f32_fp8((int)w, true);
    o[0] = lo.x; o[1] = lo.y; o[2] = hi.x; o[3] = hi.y;
#else
    #pragma unroll
    for (int c = 0; c < 4; ++c) {
        __hip_fp8_e4m3 q; q.__x = (__hip_fp8_storage_t)((w >> (8 * c)) & 0xFF);
        o[c] = (float)q;
    }
#endif
}
__device__ inline unsigned int f32x4_to_fp8(float a, float b, float c, float d) {
#if HW_FP8
    int p = __builtin_amdgcn_cvt_pk_fp8_f32(a, b, 0, false);
    p = __builtin_amdgcn_cvt_pk_fp8_f32(c, d, p, true);
    return (unsigned int)p;
#else
    __hip_fp8_e4m3 qa(a), qb(b), qc(c), qd(d);
    return (unsigned int)qa.__x | ((unsigned int)qb.__x << 8) |
           ((unsigned int)qc.__x << 16) | ((unsigned int)qd.__x << 24);
#endif
}

// ---------------------------------------------------------------------------
// Exclusive prefix scan over 256 LDS ints (all 256 threads must call).
// ---------------------------------------------------------------------------
__device__ inline void block_excl_scan_256(const int* __restrict__ arr,
                                           int* __restrict__ excl,
                                           int* __restrict__ wsum, int tid)
{
    int lane = tid & 63, w = tid >> 6;
    int v = arr[tid];
    int inc = v;
    #pragma unroll
    for (int off = 1; off < 64; off <<= 1) {
        int t = __shfl_up(inc, off, 64);
        if (lane >= off) inc += t;
    }
    if (lane == 63) wsum[w] = inc;
    __syncthreads();
    if (tid == 0) {
        int s = 0;
        #pragma unroll
        for (int i = 0; i < 4; ++i) { int t = wsum[i]; wsum[i] = s; s += t; }
    }
    __syncthreads();
    excl[tid] = inc - v + wsum[w];
    __syncthreads();
}

// ---------------------------------------------------------------------------
// prep_kernel — three independent block ranges:
//   [0, cvtB)              : x -> xq (fp8 e4m3)
//   [cvtB, cvtB+192)       : pack Wl1 / Wr1 / [Wl2|Wr2] into MFMA B-frag order
//   [cvtB+192, ...)        : bin_coarse — counting-sort pass A (dst>>8)
// ---------------------------------------------------------------------------
__global__ __launch_bounds__(256) void prep_kernel(
    const float* __restrict__ x, unsigned char* __restrict__ xq,
    const float* __restrict__ Wl1, const float* __restrict__ Wr1,
    const float* __restrict__ Wl2, const float* __restrict__ Wr2,
    unsigned short* __restrict__ W1p, unsigned short* __restrict__ W2p,
    const int* __restrict__ ei, int* __restrict__ cursor,
    unsigned int* __restrict__ coarse,
    int total8, int cvtB, int E, int nb, int cap)
{
    __shared__ int hist[256], lstart[256], gbase[256], wsum[4];
    __shared__ unsigned int staged[4096];
    const int b = blockIdx.x;
    const int tid = threadIdx.x;

    if (b < cvtB) {
        int i = b * 256 + tid;
        if (i >= total8) return;
        float4 a = ((const float4*)x)[2 * i];
        float4 c = ((const float4*)x)[2 * i + 1];
        uint2 pk;
        pk.x = f32x4_to_fp8(a.x, a.y, a.z, a.w);
        pk.y = f32x4_to_fp8(c.x, c.y, c.z, c.w);
        *(uint2*)(xq + (size_t)i * 8) = pk;
        return;
    }
    if (b < cvtB + 192) {
        int region = (b - cvtB) >> 6;
        int idx = ((b - cvtB) & 63) * 256 + tid;   // 0..16383
        int k = idx >> 7, c = idx & 127;
        int d = ((k >> 5) * 8 + (c >> 4)) * 512 + ((k >> 3) & 3) * 128 + (c & 15) * 8 + (k & 7);
        if (region == 0)      W1p[d] = f2bf(Wl1[idx]);
        else if (region == 1) W1p[128 * 128 + d] = f2bf(Wr1[idx]);
        else {
            float v = (c < 64) ? Wl2[k * 64 + c] : Wr2[k * 64 + (c - 64)];
            W2p[d] = f2bf(v);
        }
        return;
    }

    // ---- bin_coarse ----
    const int chunkBase = (b - cvtB - 192) * 4096;
    hist[tid] = 0;
    __syncthreads();

    unsigned int rec[16]; int pos[16]; int bb[16];
    #pragma unroll
    for (int i = 0; i < 16; ++i) {
        int e = chunkBase + i * 256 + tid;
        if (e < E) {
            int s = ei[e], d = ei[E + e];
            rec[i] = ((unsigned int)d << 16) | (unsigned int)s;
            bb[i]  = d >> 8;
            pos[i] = atomicAdd(&hist[bb[i]], 1);
        } else bb[i] = -1;
    }
    __syncthreads();

    block_excl_scan_256(hist, lstart, wsum, tid);

    if (tid < nb) {
        int c = hist[tid];
        gbase[tid] = c ? atomicAdd(&cursor[tid], c) : 0;
    }
    __syncthreads();

    #pragma unroll
    for (int i = 0; i < 16; ++i)
        if (bb[i] >= 0) staged[lstart[bb[i]] + pos[i]] = rec[i];
    __syncthreads();

    int total = min(4096, E - chunkBase);
    for (int i = tid; i < total; i += 256) {
        unsigned int r = staged[i];
        int bk  = (int)(r >> 24);
        int gp  = gbase[bk] + (i - lstart[bk]);
        if (gp < cap) coarse[(size_t)bk * cap + gp] = r;
    }
}

// ---------------------------------------------------------------------------
// Counting sort pass B: one block per coarse bucket; scatter src (ushort)
// into bucket-owned window; emit deg / row_start.
// ---------------------------------------------------------------------------
__global__ __launch_bounds__(256) void bin_fine(
    const int* __restrict__ cursor, const unsigned int* __restrict__ coarse,
    unsigned short* __restrict__ sorted, int* __restrict__ deg,
    int* __restrict__ row_start, int n, int cap)
{
    __shared__ int hist[256], pstart[256], cur2[256], wsum[4];
    const int b = blockIdx.x, tid = threadIdx.x;
    const int cnt = min(cursor[b], cap);
    const unsigned int* src = coarse + (size_t)b * cap;

    hist[tid] = 0;
    __syncthreads();

    int nIter = (cnt + 255) >> 8;
    for (int i = 0; i < nIter; ++i) {
        int idx = i * 256 + tid;
        if (idx < cnt) atomicAdd(&hist[(src[idx] >> 16) & 255], 1);
    }
    __syncthreads();

    block_excl_scan_256(hist, pstart, wsum, tid);
    cur2[tid] = pstart[tid];
    __syncthreads();

    for (int i = 0; i < nIter; ++i) {
        int idx = i * 256 + tid;
        if (idx < cnt) {
            unsigned int r = src[idx];
            int dl = (r >> 16) & 255;
            int p  = atomicAdd(&cur2[dl], 1);
            sorted[(size_t)b * cap + p] = (unsigned short)(r & 0xFFFFu);
        }
    }

    int node = b * 256 + tid;
    if (node < n) {
        deg[node]       = hist[tid];
        row_start[node] = b * cap + pstart[tid];
    }
}

// ---------------------------------------------------------------------------
// GEMM1 fused with layer-1 gather.
//   G-tile: per-row gather-mean of fp8 neighbors. 8 rows/wave x 8 lanes/row;
//   8-way unrolled batch loads (8 indices then 8 row-slices in flight) for
//   memory-level parallelism (R9's serial chain was the 62us bottleneck).
//   X frags: loaded DIRECTLY from fp32 x (A-frag = 8 contiguous k per lane),
//   converted in registers -> no X LDS tile, no xb buffer.
//   No barrier between G fill and MFMA (wave reads only its own rows).
// ---------------------------------------------------------------------------
__global__ __launch_bounds__(256) void gemm1_fused(
    const unsigned char* __restrict__ xq, const float* __restrict__ x,
    const int* __restrict__ row_start, const int* __restrict__ deg,
    const unsigned short* __restrict__ sorted,
    const unsigned short* __restrict__ W1p, const float* __restrict__ bias,
    unsigned short* __restrict__ hb,
    float* __restrict__ bn_sum, float* __restrict__ bn_sumsq, int n)
{
    __shared__ unsigned short G[64][136];
    __shared__ float red[2][4][128];

    const int block_row = blockIdx.x * 64;
    const int tid  = threadIdx.x;
    const int wave = tid >> 6;
    const int lane = tid & 63;
    const int q    = lane >> 4;
    const int m16  = lane & 15;

    // ---- gather own 16 rows into G: 2 groups of 8 rows, 8 lanes/row ----
    {
        int sub = lane & 7, oct = lane >> 3;
        #pragma unroll
        for (int grp = 0; grp < 2; ++grp) {
            int lr = wave * 16 + grp * 8 + oct;
            int g  = block_row + lr;
            float acc[16];
            #pragma unroll
            for (int j = 0; j < 16; ++j) acc[j] = 0.f;
            int d = 0;
            if (g < n) {
                int base = row_start[g];
                d = deg[g];
                int t = 0;
                for (; t + 8 <= d; t += 8) {
                    uint4 raws[8];
                    #pragma unroll
                    for (int u = 0; u < 8; ++u) {
                        int s = (int)sorted[base + t + u];
                        raws[u] = ((const uint4*)(xq + (size_t)s * DIN))[sub];
                    }
                    #pragma unroll
                    for (int u = 0; u < 8; ++u) {
                        const unsigned int* w = (const unsigned int*)&raws[u];
                        #pragma unroll
                        for (int c = 0; c < 4; ++c) {
                            float o4[4];
                            fp8x4_to_f32(w[c], o4);
                            acc[c*4+0] += o4[0]; acc[c*4+1] += o4[1];
                            acc[c*4+2] += o4[2]; acc[c*4+3] += o4[3];
                        }
                    }
                }
                for (; t < d; ++t) {
                    int s = (int)sorted[base + t];
                    uint4 raw = ((const uint4*)(xq + (size_t)s * DIN))[sub];
                    const unsigned int* w = (const unsigned int*)&raw;
                    #pragma unroll
                    for (int c = 0; c < 4; ++c) {
                        float o4[4];
                        fp8x4_to_f32(w[c], o4);
                        acc[c*4+0] += o4[0]; acc[c*4+1] += o4[1];
                        acc[c*4+2] += o4[2]; acc[c*4+3] += o4[3];
                    }
                }
            }
            float inv = 1.0f / fmaxf((float)d, 1.0f);
            unsigned short t16[16];
            #pragma unroll
            for (int j = 0; j < 16; ++j) t16[j] = f2bf(acc[j] * inv);
            *(uint4*)&G[lr][sub * 16]     = ((uint4*)t16)[0];
            *(uint4*)&G[lr][sub * 16 + 8] = ((uint4*)t16)[1];
        }
    }
    // no __syncthreads: each wave reads only rows it wrote.

    f32x4 acc[8];
    #pragma unroll
    for (int nt = 0; nt < 8; ++nt) acc[nt] = (f32x4){0.f, 0.f, 0.f, 0.f};

    const int grow = block_row + wave * 16 + m16;   // this lane's A row
    #pragma unroll
    for (int ks = 0; ks < 4; ++ks) {
        bf16x8 ag = *(const bf16x8*)&G[wave * 16 + m16][ks * 32 + q * 8];
        const unsigned short* wp0 = W1p + (size_t)ks * 8 * 512;          // Wl1
        #pragma unroll
        for (int nt = 0; nt < 8; ++nt) {
            bf16x8 b = *(const bf16x8*)(wp0 + nt * 512 + lane * 8);
            acc[nt] = __builtin_amdgcn_mfma_f32_16x16x32_bf16(ag, b, acc[nt], 0, 0, 0);
        }
        // X frag direct from fp32 x, converted in regs
        bf16x8 ax;
        {
            float4 f0 = {0.f,0.f,0.f,0.f}, f1 = {0.f,0.f,0.f,0.f};
            if (grow < n) {
                const float* xr = x + (size_t)grow * DIN + ks * 32 + q * 8;
                f0 = *(const float4*)xr;
                f1 = *(const float4*)(xr + 4);
            }
            unsigned short t[8];
            t[0]=f2bf(f0.x); t[1]=f2bf(f0.y); t[2]=f2bf(f0.z); t[3]=f2bf(f0.w);
            t[4]=f2bf(f1.x); t[5]=f2bf(f1.y); t[6]=f2bf(f1.z); t[7]=f2bf(f1.w);
            ax = *(bf16x8*)t;
        }
        const unsigned short* wp1 = W1p + (size_t)(4 + ks) * 8 * 512;    // Wr1
        #pragma unroll
        for (int nt = 0; nt < 8; ++nt) {
            bf16x8 b = *(const bf16x8*)(wp1 + nt * 512 + lane * 8);
            acc[nt] = __builtin_amdgcn_mfma_f32_16x16x32_bf16(ax, b, acc[nt], 0, 0, 0);
        }
    }

    // ---- epilogue: bias, hb store, BN partials ----
    float psum[8], psq[8];
    #pragma unroll
    for (int nt = 0; nt < 8; ++nt) {
        int col = nt * 16 + m16;
        float bv = bias[col];
        float s = 0.f, ssq = 0.f;
        #pragma unroll
        for (int reg = 0; reg < 4; ++reg) {
            int g = block_row + wave * 16 + q * 4 + reg;
            float v = acc[nt][reg] + bv;
            if (g < n) {
                hb[(size_t)g * DH + col] = f2bf(v);
                s += v; ssq += v * v;
            }
        }
        psum[nt] = s; psq[nt] = ssq;
    }
    #pragma unroll
    for (int nt = 0; nt < 8; ++nt) {
        psum[nt] += __shfl_xor(psum[nt], 16, 64);
        psum[nt] += __shfl_xor(psum[nt], 32, 64);
        psq[nt]  += __shfl_xor(psq[nt], 16, 64);
        psq[nt]  += __shfl_xor(psq[nt], 32, 64);
    }
    if (lane < 16) {
        #pragma unroll
        for (int nt = 0; nt < 8; ++nt) {
            red[0][wave][nt * 16 + lane] = psum[nt];
            red[1][wave][nt * 16 + lane] = psq[nt];
        }
    }
    __syncthreads();
    if (tid < 128) {
        float s = red[0][0][tid] + red[0][1][tid] + red[0][2][tid] + red[0][3][tid];
        float ssq = red[1][0][tid] + red[1][1][tid] + red[1][2][tid] + red[1][3][tid];
        atomicAdd(&bn_sum[tid], s);
        atomicAdd(&bn_sumsq[tid], ssq);
    }
}

// ---------------------------------------------------------------------------
// GEMM2 (MFMA bf16): BN finalize in LDS; A-frags loaded directly from hb and
// BN+ReLU applied in registers (no LDS A tile).
// cols 0..63 -> P = a@Wl2 (bf16), cols 64..127 -> out = a@Wr2 + b2 (fp32).
// ---------------------------------------------------------------------------
__global__ __launch_bounds__(256) void gemm2p_mfma(
    const unsigned short* __restrict__ hb,
    const float* __restrict__ bn_sum, const float* __restrict__ bn_sumsq,
    const float* __restrict__ gamma, const float* __restrict__ beta,
    const unsigned short* __restrict__ W2p, const float* __restrict__ bias,
    unsigned short* __restrict__ P, float* __restrict__ out, int n)
{
    __shared__ float s_scale[128], s_shift[128];

    const int block_row = blockIdx.x * 64;
    const int tid  = threadIdx.x;
    const int wave = tid >> 6;
    const int lane = tid & 63;
    const int q    = lane >> 4;
    const int m16  = lane & 15;

    if (tid < 128) {
        float invN = 1.0f / (float)n;
        float mu  = bn_sum[tid] * invN;
        float var = bn_sumsq[tid] * invN - mu * mu;
        float sc  = gamma[tid] * rsqrtf(var + BN_EPS);
        s_scale[tid] = sc;
        s_shift[tid] = beta[tid] - mu * sc;
    }
    __syncthreads();

    f32x4 acc[8];
    #pragma unroll
    for (int nt = 0; nt < 8; ++nt) acc[nt] = (f32x4){0.f, 0.f, 0.f, 0.f};

    const int grow = block_row + wave * 16 + m16;
    #pragma unroll
    for (int ks = 0; ks < 4; ++ks) {
        bf16x8 a;
        {
            int kbase = ks * 32 + q * 8;
            float4 sc0 = *(const float4*)&s_scale[kbase];
            float4 sc1 = *(const float4*)&s_scale[kbase + 4];
            float4 sh0 = *(const float4*)&s_shift[kbase];
            float4 sh1 = *(const float4*)&s_shift[kbase + 4];
            unsigned short t[8] = {0,0,0,0,0,0,0,0};
            if (grow < n) {
                uint4 raw = *(const uint4*)(hb + (size_t)grow * DH + kbase);
                const unsigned short* u = (const unsigned short*)&raw;
                t[0] = f2bf(fmaxf(bf2f(u[0]) * sc0.x + sh0.x, 0.f));
                t[1] = f2bf(fmaxf(bf2f(u[1]) * sc0.y + sh0.y, 0.f));
                t[2] = f2bf(fmaxf(bf2f(u[2]) * sc0.z + sh0.z, 0.f));
                t[3] = f2bf(fmaxf(bf2f(u[3]) * sc0.w + sh0.w, 0.f));
                t[4] = f2bf(fmaxf(bf2f(u[4]) * sc1.x + sh1.x, 0.f));
                t[5] = f2bf(fmaxf(bf2f(u[5]) * sc1.y + sh1.y, 0.f));
                t[6] = f2bf(fmaxf(bf2f(u[6]) * sc1.z + sh1.z, 0.f));
                t[7] = f2bf(fmaxf(bf2f(u[7]) * sc1.w + sh1.w, 0.f));
            }
            a = *(bf16x8*)t;
        }
        const unsigned short* wp = W2p + (size_t)ks * 8 * 512;
        #pragma unroll
        for (int nt = 0; nt < 8; ++nt) {
            bf16x8 b = *(const bf16x8*)(wp + nt * 512 + lane * 8);
            acc[nt] = __builtin_amdgcn_mfma_f32_16x16x32_bf16(a, b, acc[nt], 0, 0, 0);
        }
    }

    #pragma unroll
    for (int nt = 0; nt < 4; ++nt) {
        int col = nt * 16 + m16;
        #pragma unroll
        for (int reg = 0; reg < 4; ++reg) {
            int g = block_row + wave * 16 + q * 4 + reg;
            if (g < n) P[(size_t)g * DOUTC + col] = f2bf(acc[nt][reg]);
        }
    }
    #pragma unroll
    for (int nt = 4; nt < 8; ++nt) {
        int col = (nt - 4) * 16 + m16;
        float bv = bias[col];
        #pragma unroll
        for (int reg = 0; reg < 4; ++reg) {
            int g = block_row + wave * 16 + q * 4 + reg;
            if (g < n) out[(size_t)g * DOUTC + col] = acc[nt][reg] + bv;
        }
    }
}

// ---------------------------------------------------------------------------
// Layer-2 gather-mean over bf16 P rows, shfl-free with 8-way batch-load ILP.
// 8 rows/wave, 8 lanes/row; each lane owns a 16B slice.
// ---------------------------------------------------------------------------
__global__ __launch_bounds__(256) void agg_gather64_add(
    const int* __restrict__ row_start, const int* __restrict__ deg,
    const unsigned short* __restrict__ sorted, const unsigned short* __restrict__ P,
    float* __restrict__ out, int n)
{
    int wid  = (blockIdx.x * 256 + threadIdx.x) >> 6;
    int lane = threadIdx.x & 63;
    int sub = lane & 7, oct = lane >> 3;
    int r = wid * 8 + oct;
    if (r >= n) return;

    float acc[8];
    #pragma unroll
    for (int j = 0; j < 8; ++j) acc[j] = 0.f;

    int base = row_start[r];
    int d    = deg[r];
    int t = 0;
    for (; t + 8 <= d; t += 8) {
        uint4 raws[8];
        #pragma unroll
        for (int u = 0; u < 8; ++u) {
            int s = (int)sorted[base + t + u];
            raws[u] = ((const uint4*)(P + (size_t)s * DOUTC))[sub];
        }
        #pragma unroll
        for (int u = 0; u < 8; ++u) {
            const unsigned short* us = (const unsigned short*)&raws[u];
            #pragma unroll
            for (int j = 0; j < 8; ++j) acc[j] += bf2f(us[j]);
        }
    }
    for (; t < d; ++t) {
        int s = (int)sorted[base + t];
        uint4 raw = ((const uint4*)(P + (size_t)s * DOUTC))[sub];
        const unsigned short* us = (const unsigned short*)&raw;
        #pragma unroll
        for (int j = 0; j < 8; ++j) acc[j] += bf2f(us[j]);
    }
    float inv = 1.0f / fmaxf((float)d, 1.0f);
    float* op = out + (size_t)r * DOUTC + sub * 8;
    float4 c0 = *(float4*)op;
    float4 c1 = *((float4*)op + 1);
    c0.x += acc[0] * inv; c0.y += acc[1] * inv;
    c0.z += acc[2] * inv; c0.w += acc[3] * inv;
    c1.x += acc[4] * inv; c1.y += acc[5] * inv;
    c1.z += acc[6] * inv; c1.w += acc[7] * inv;
    *(float4*)op = c0;
    *((float4*)op + 1) = c1;
}

// ---------------------------------------------------------------------------
extern "C" void kernel_launch(void* const* d_in, const int* in_sizes, int n_in,
                              void* d_out, int out_size, void* d_ws, size_t ws_size,
                              hipStream_t stream)
{
    const float* x     = (const float*)d_in[0];
    const int*   ei    = (const int*)  d_in[1];
    const float* Wl1   = (const float*)d_in[2];
    const float* Wr1   = (const float*)d_in[3];
    const float* b1    = (const float*)d_in[4];
    const float* gamma = (const float*)d_in[5];
    const float* beta  = (const float*)d_in[6];
    const float* Wl2   = (const float*)d_in[7];
    const float* Wr2   = (const float*)d_in[8];
    const float* b2    = (const float*)d_in[9];
    float*       out   = (float*)d_out;

    const int N = in_sizes[0] / DIN;      // 50000
    const int E = in_sizes[1] / 2;        // 800000

    const int NB  = (N + 255) >> 8;                       // coarse buckets
    int cap = (E / NB) * 3 / 2 + 256;
    cap = (cap + 255) & ~255;

    // workspace layout (segments 16B-aligned)
    float* bn_sum   = (float*)d_ws;                       // 128
    float* bn_sumsq = bn_sum + DH;                        // 128
    int* cursor     = (int*)(bn_sumsq + DH);              // 256
    int* deg        = cursor + 256;                       // N
    int* row_start  = deg + N;                            // N
    unsigned int* coarse   = (unsigned int*)(row_start + N);            // NB*cap
    unsigned short* sorted = (unsigned short*)(coarse + (size_t)NB * cap);
    unsigned short* hb     = sorted + (size_t)NB * cap;   // N*128 bf16
    unsigned short* P      = hb + (size_t)N * DH;         // N*64 bf16
    unsigned short* W1p    = P + (size_t)N * DOUTC;       // 256*128 bf16
    unsigned short* W2p    = W1p + 256 * 128;             // 128*128 bf16
    unsigned char*  xq     = (unsigned char*)(W2p + 128 * 128); // N*128 fp8

    // zero bn sums + coarse cursors
    hipMemsetAsync(bn_sum, 0, (2 * DH + 256) * sizeof(float), stream);

    dim3 blk(256);
    const int cvtB        = (N * DIN / 8 + 255) / 256;        // 3125
    const int binA_blocks = (E + 4095) / 4096;                // 196
    const int gemm_blocks = (N + 63) / 64;
    const int g64_blocks  = ((N + 7) / 8 + 3) / 4;

    // ---- prep: x-quantize | weight-pack | coarse-bin (one launch) ----
    prep_kernel<<<cvtB + 192 + binA_blocks, blk, 0, stream>>>(
        x, xq, Wl1, Wr1, Wl2, Wr2, W1p, W2p,
        ei, cursor, coarse, N * DIN / 8, cvtB, E, NB, cap);

    // ---- counting sort pass B ----
    bin_fine<<<NB, blk, 0, stream>>>(cursor, coarse, sorted, deg, row_start, N, cap);

    // ---- layer 1: fused gather + GEMM + BN partials ----
    gemm1_fused<<<gemm_blocks, blk, 0, stream>>>(xq, x, row_start, deg, sorted,
                                                 W1p, b1, hb, bn_sum, bn_sumsq, N);

    // ---- layer 2: BN finalize + ReLU + project ----
    gemm2p_mfma<<<gemm_blocks, blk, 0, stream>>>(hb, bn_sum, bn_sumsq,
                                                 gamma, beta, W2p, b2, P, out, N);

    // ---- layer 2 aggregation ----
    agg_gather64_add<<<g64_blocks, blk, 0, stream>>>(row_start, deg, sorted,
                                                     P, out, N);
}